// Round 11
// baseline (321.014 us; speedup 1.0000x reference)
//
#include <hip/hip_runtime.h>

#define ODIM 128          // OUT_DIM
#define BROWS 128         // rows per bucket
#define NBMAX 512         // max buckets (N/128 = 391 for N=50000)
#define TILE 2560         // edges per partition tile (fits 40KB LDS plan)
#define CMASK 0x1FFFFu    // low 17 bits of meta = col
#define PREP_GRID 512     // 2 blocks/CU guaranteed co-resident
#define PREP_THREADS 256

typedef unsigned u32;

__device__ inline unsigned f2bf(float x) {  // fp32 -> bf16 bits, RNE
  unsigned u = __float_as_uint(x);
  return (u + 0x7fffu + ((u >> 16) & 1u)) >> 16;
}

// ---- soft grid barrier (co-residency guaranteed by launch_bounds + LDS) ----
__device__ inline void grid_bar(unsigned* cnt, unsigned nblk) {
  __syncthreads();
  if (threadIdx.x == 0) {
    __threadfence();  // device-scope release of prior plain stores
    unsigned arrived =
        __hip_atomic_fetch_add(cnt, 1u, __ATOMIC_ACQ_REL, __HIP_MEMORY_SCOPE_AGENT) + 1u;
    if (arrived < nblk) {
      while (__hip_atomic_load(cnt, __ATOMIC_ACQUIRE, __HIP_MEMORY_SCOPE_AGENT) < nblk)
        __builtin_amdgcn_s_sleep(2);
    }
  }
  __syncthreads();
}

// ---- one persistent kernel: zero+convW | hist | scan | partition | bucket sort ----
__global__ __launch_bounds__(PREP_THREADS, 2) void prep_all(
    const int* __restrict__ xr, const int* __restrict__ xc,
    const float* __restrict__ xv, int nx,
    const int* __restrict__ ar, const int* __restrict__ ac,
    const float* __restrict__ av, int na,
    const float2* __restrict__ W2, u32* __restrict__ Wbf, int wwords,
    int* __restrict__ ghX, int* __restrict__ ghA,
    int* __restrict__ baseX, int* __restrict__ baseA,
    int* __restrict__ curX, int* __restrict__ curA,
    uint2* __restrict__ bufPX, uint2* __restrict__ bufPA,
    uint2* __restrict__ bufSX, uint2* __restrict__ bufSA,
    int* __restrict__ rpX, int* __restrict__ rpA,
    int N, int nb, int ntX, int ntA, unsigned* __restrict__ bars) {
  __shared__ __align__(16) char smem[40960];
  const int tid = threadIdx.x;
  const int bid = blockIdx.x;
  const int gsize = PREP_GRID * PREP_THREADS;
  const int gtid = bid * PREP_THREADS + tid;

  // ---- phase A: zero hists + convert W to packed bf16 ----
  for (int i = gtid; i < 2 * NBMAX; i += gsize) {
    if (i < NBMAX) ghX[i] = 0;
    else           ghA[i - NBMAX] = 0;
  }
  for (int i = gtid; i < wwords; i += gsize) {
    float2 w = W2[i];
    Wbf[i] = f2bf(w.x) | (f2bf(w.y) << 16);
  }
  grid_bar(&bars[0], PREP_GRID);

  // ---- phase B: bucket histogram (private LDS hist -> atomic merge) ----
  {
    int* lh = (int*)smem;  // 2*NBMAX ints = 4KB
    for (int i = tid; i < 2 * NBMAX; i += PREP_THREADS) lh[i] = 0;
    __syncthreads();
    int total = nx + na;
    for (int i = gtid; i < total; i += gsize) {
      if (i < nx) atomicAdd(&lh[xr[i] >> 7], 1);
      else        atomicAdd(&lh[NBMAX + (ar[i - nx] >> 7)], 1);
    }
    __syncthreads();
    for (int b = tid; b < NBMAX; b += PREP_THREADS) {
      if (lh[b])         atomicAdd(&ghX[b], lh[b]);
      if (lh[NBMAX + b]) atomicAdd(&ghA[b], lh[NBMAX + b]);
    }
  }
  grid_bar(&bars[1], PREP_GRID);

  // ---- phase C: exclusive scan of 512 bins (block 0: X, block 1: A) ----
  if (bid < 2) {
    int* gh   = bid ? ghA   : ghX;
    int* base = bid ? baseA : baseX;
    int* cur  = bid ? curA  : curX;
    int* s = (int*)smem;  // 256 ints
    int h0 = gh[2 * tid], h1 = gh[2 * tid + 1];
    int psum = h0 + h1;
    s[tid] = psum;
    __syncthreads();
    for (int off = 1; off < 256; off <<= 1) {
      int t = (tid >= off) ? s[tid - off] : 0;
      __syncthreads();
      s[tid] += t;
      __syncthreads();
    }
    int excl = s[tid] - psum;
    base[2 * tid] = excl;     base[2 * tid + 1] = excl + h0;
    cur[2 * tid]  = excl;     cur[2 * tid + 1]  = excl + h0;
    if (tid == 255) base[NBMAX] = s[255];
  }
  grid_bar(&bars[2], PREP_GRID);

  // ---- phase D: tile counting-sort into buckets (coalesced runs) ----
  {
    uint2* pay           = (uint2*)smem;                    // 20480B
    unsigned short* bkt  = (unsigned short*)(smem + 20480); // 5120B
    unsigned short* perm = (unsigned short*)(smem + 25600); // 5120B
    int* hist            = (int*)(smem + 30720);            // 2048B
    int* scn             = (int*)(smem + 32768);            // 2048B
    int* lcur            = (int*)(smem + 34816);            // 2048B
    int* gbase           = (int*)(smem + 36864);            // 2048B
    int* part            = (int*)(smem + 38912);            // 1024B
    const int ntot = ntX + ntA;
    for (int t = bid; t < ntot; t += PREP_GRID) {
      const int* rows; const int* cols; const float* vals;
      int nnz; int* gcur; uint2* outbuf; int tile;
      if (t < ntX) { rows = xr; cols = xc; vals = xv; nnz = nx; gcur = curX; outbuf = bufPX; tile = t; }
      else         { rows = ar; cols = ac; vals = av; nnz = na; gcur = curA; outbuf = bufPA; tile = t - ntX; }
      int tbase = tile * TILE;
      int cnt = nnz - tbase; if (cnt > TILE) cnt = TILE;
      __syncthreads();  // protect LDS reuse across loop iterations
      for (int b = tid; b < NBMAX; b += PREP_THREADS) hist[b] = 0;
      __syncthreads();
      for (int j = tid; j < cnt; j += PREP_THREADS) {
        int r = rows[tbase + j];
        int c = cols[tbase + j];
        float v = vals[tbase + j];
        unsigned bb = (unsigned)r >> 7;
        bkt[j] = (unsigned short)bb;
        pay[j] = make_uint2(((unsigned)(r & 127) << 17) | (unsigned)c, __float_as_uint(v));
        atomicAdd(&hist[bb], 1);
      }
      __syncthreads();
      int h0 = hist[2 * tid], h1 = hist[2 * tid + 1];
      int psum = h0 + h1;
      part[tid] = psum;
      __syncthreads();
      for (int off = 1; off < 256; off <<= 1) {
        int tv = (tid >= off) ? part[tid - off] : 0;
        __syncthreads();
        part[tid] += tv;
        __syncthreads();
      }
      int excl = part[tid] - psum;
      scn[2 * tid] = excl;    scn[2 * tid + 1] = excl + h0;
      lcur[2 * tid] = excl;   lcur[2 * tid + 1] = excl + h0;
      __syncthreads();
      for (int j = tid; j < cnt; j += PREP_THREADS) {
        int pos = atomicAdd(&lcur[bkt[j]], 1);
        perm[pos] = (unsigned short)j;
      }
      for (int b = tid; b < NBMAX; b += PREP_THREADS) {
        int c2 = hist[b];
        if (c2) gbase[b] = atomicAdd(&gcur[b], c2);
      }
      __syncthreads();
      for (int pp = tid; pp < cnt; pp += PREP_THREADS) {
        int j = perm[pp];
        int bb = bkt[j];
        outbuf[gbase[bb] + (pp - scn[bb])] = pay[j];
      }
    }
  }
  grid_bar(&bars[3], PREP_GRID);

  // ---- phase E: per-bucket exact row sort + rowptr ----
  {
    int* hist = (int*)smem;           // 512B
    int* scn  = (int*)(smem + 512);   // 512B
    int* lcur = (int*)(smem + 1024);  // 512B
    for (int u2 = bid; u2 < 2 * nb; u2 += PREP_GRID) {
      const int* bbase; const uint2* bin; uint2* bout; int* rowptr; int b;
      if (u2 < nb) { bbase = baseX; bin = bufPX; bout = bufSX; rowptr = rpX; b = u2; }
      else         { bbase = baseA; bin = bufPA; bout = bufSA; rowptr = rpA; b = u2 - nb; }
      int e0 = bbase[b], ecnt = bbase[b + 1] - e0;
      __syncthreads();  // protect LDS reuse across loop iterations
      if (tid < BROWS) hist[tid] = 0;
      __syncthreads();
      for (int j = tid; j < ecnt; j += PREP_THREADS)
        atomicAdd(&hist[bin[e0 + j].x >> 17], 1);
      __syncthreads();
      int v = (tid < BROWS) ? hist[tid] : 0;
      if (tid < BROWS) scn[tid] = v;
      __syncthreads();
      for (int off = 1; off < BROWS; off <<= 1) {
        int tt = (tid < BROWS && tid >= off) ? scn[tid - off] : 0;
        __syncthreads();
        if (tid < BROWS) scn[tid] += tt;
        __syncthreads();
      }
      if (tid < BROWS) {
        int excl = scn[tid] - v;
        lcur[tid] = excl;
        int node = b * BROWS + tid;
        if (node <= N) rowptr[node] = e0 + excl;
      }
      __syncthreads();
      for (int j = tid; j < ecnt; j += PREP_THREADS) {
        uint2 e = bin[e0 + j];
        int pos = atomicAdd(&lcur[e.x >> 17], 1);
        bout[e0 + pos] = e;
      }
    }
  }
}

// ---------------- pulls (wave per row, register accumulate, 8-deep) ---------
// B word l of a row = bf16(dim 2l) | bf16(dim 2l+1)<<16.

__global__ __launch_bounds__(256) void pull_x(
    const int* __restrict__ rowptr, const uint2* __restrict__ cv,
    const u32* __restrict__ Wbf, unsigned* __restrict__ xw, int nrows) {
  int lane = threadIdx.x & 63;
  int r = blockIdx.x * 4 + (threadIdx.x >> 6);
  if (r >= nrows) return;
  int e = rowptr[r], end = rowptr[r + 1];
  float acc0[8], acc1[8];
#pragma unroll
  for (int u = 0; u < 8; ++u) { acc0[u] = 0.f; acc1[u] = 0.f; }
  for (; e + 7 < end; e += 8) {
    uint2 ed[8]; unsigned xg[8];
#pragma unroll
    for (int u = 0; u < 8; ++u) ed[u] = cv[e + u];
#pragma unroll
    for (int u = 0; u < 8; ++u)
      xg[u] = Wbf[(size_t)(ed[u].x & CMASK) * 64 + lane];
#pragma unroll
    for (int u = 0; u < 8; ++u) {
      float v = __uint_as_float(ed[u].y);
      acc0[u] += v * __uint_as_float(xg[u] << 16);
      acc1[u] += v * __uint_as_float(xg[u] & 0xffff0000u);
    }
  }
  for (; e + 1 < end; e += 2) {
    uint2 ea = cv[e], eb = cv[e + 1];
    unsigned ua = Wbf[(size_t)(ea.x & CMASK) * 64 + lane];
    unsigned ub = Wbf[(size_t)(eb.x & CMASK) * 64 + lane];
    float va = __uint_as_float(ea.y), vb = __uint_as_float(eb.y);
    acc0[0] += va * __uint_as_float(ua << 16);
    acc1[0] += va * __uint_as_float(ua & 0xffff0000u);
    acc0[1] += vb * __uint_as_float(ub << 16);
    acc1[1] += vb * __uint_as_float(ub & 0xffff0000u);
  }
  if (e < end) {
    uint2 ea = cv[e];
    unsigned ua = Wbf[(size_t)(ea.x & CMASK) * 64 + lane];
    float va = __uint_as_float(ea.y);
    acc0[2] += va * __uint_as_float(ua << 16);
    acc1[2] += va * __uint_as_float(ua & 0xffff0000u);
  }
  float o0 = ((acc0[0] + acc0[1]) + (acc0[2] + acc0[3])) +
             ((acc0[4] + acc0[5]) + (acc0[6] + acc0[7]));
  float o1 = ((acc1[0] + acc1[1]) + (acc1[2] + acc1[3])) +
             ((acc1[4] + acc1[5]) + (acc1[6] + acc1[7]));
  xw[(size_t)r * 64 + lane] = f2bf(o0) | (f2bf(o1) << 16);
}

__global__ __launch_bounds__(256) void pull_a(
    const int* __restrict__ rowptr, const uint2* __restrict__ cv,
    const unsigned* __restrict__ xw, float2* __restrict__ out, int nrows) {
  int lane = threadIdx.x & 63;
  int r = blockIdx.x * 4 + (threadIdx.x >> 6);
  if (r >= nrows) return;
  int e = rowptr[r], end = rowptr[r + 1];
  float acc0[8], acc1[8];
#pragma unroll
  for (int u = 0; u < 8; ++u) { acc0[u] = 0.f; acc1[u] = 0.f; }
  for (; e + 7 < end; e += 8) {
    uint2 ed[8]; unsigned xg[8];
#pragma unroll
    for (int u = 0; u < 8; ++u) ed[u] = cv[e + u];
#pragma unroll
    for (int u = 0; u < 8; ++u)
      xg[u] = xw[(size_t)(ed[u].x & CMASK) * 64 + lane];
#pragma unroll
    for (int u = 0; u < 8; ++u) {
      float v = __uint_as_float(ed[u].y);
      acc0[u] += v * __uint_as_float(xg[u] << 16);
      acc1[u] += v * __uint_as_float(xg[u] & 0xffff0000u);
    }
  }
  for (; e + 1 < end; e += 2) {
    uint2 ea = cv[e], eb = cv[e + 1];
    unsigned ua = xw[(size_t)(ea.x & CMASK) * 64 + lane];
    unsigned ub = xw[(size_t)(eb.x & CMASK) * 64 + lane];
    float va = __uint_as_float(ea.y), vb = __uint_as_float(eb.y);
    acc0[0] += va * __uint_as_float(ua << 16);
    acc1[0] += va * __uint_as_float(ua & 0xffff0000u);
    acc0[1] += vb * __uint_as_float(ub << 16);
    acc1[1] += vb * __uint_as_float(ub & 0xffff0000u);
  }
  if (e < end) {
    uint2 ea = cv[e];
    unsigned ua = xw[(size_t)(ea.x & CMASK) * 64 + lane];
    float va = __uint_as_float(ea.y);
    acc0[2] += va * __uint_as_float(ua << 16);
    acc1[2] += va * __uint_as_float(ua & 0xffff0000u);
  }
  float o0 = ((acc0[0] + acc0[1]) + (acc0[2] + acc0[3])) +
             ((acc0[4] + acc0[5]) + (acc0[6] + acc0[7]));
  float o1 = ((acc1[0] + acc1[1]) + (acc1[2] + acc1[3])) +
             ((acc1[4] + acc1[5]) + (acc1[6] + acc1[7]));
  out[(size_t)r * 64 + lane] = make_float2(fmaxf(o0, 0.f), fmaxf(o1, 0.f));
}

// ---------------- fallback (atomic push) ----------------

__global__ __launch_bounds__(256) void spmm_scatter(
    const int* __restrict__ rows, const int* __restrict__ cols,
    const float* __restrict__ vals, const float* __restrict__ B,
    float* __restrict__ out, int nnz) {
  int e = blockIdx.x * 2 + (threadIdx.x >> 7);
  int d = threadIdx.x & (ODIM - 1);
  if (e >= nnz) return;
  atomicAdd(&out[(size_t)rows[e] * ODIM + d],
            vals[e] * B[(size_t)cols[e] * ODIM + d]);
}

__global__ __launch_bounds__(256) void relu_inplace(float* __restrict__ p, long n4) {
  long i = (long)blockIdx.x * blockDim.x + threadIdx.x;
  long stride = (long)gridDim.x * blockDim.x;
  float4* p4 = (float4*)p;
  for (long j = i; j < n4; j += stride) {
    float4 v = p4[j];
    v.x = fmaxf(v.x, 0.f); v.y = fmaxf(v.y, 0.f);
    v.z = fmaxf(v.z, 0.f); v.w = fmaxf(v.w, 0.f);
    p4[j] = v;
  }
}

extern "C" void kernel_launch(void* const* d_in, const int* in_sizes, int n_in,
                              void* d_out, int out_size, void* d_ws, size_t ws_size,
                              hipStream_t stream) {
  const int*   x_rows   = (const int*)d_in[0];
  const int*   x_cols   = (const int*)d_in[1];
  const float* x_vals   = (const float*)d_in[2];
  const int*   adj_rows = (const int*)d_in[3];
  const int*   adj_cols = (const int*)d_in[4];
  const float* adj_vals = (const float*)d_in[5];
  const float* W        = (const float*)d_in[6];

  const int nnz_x   = in_sizes[0];
  const int nnz_adj = in_sizes[3];
  const int wlen    = in_sizes[6];              // IN_DIM * ODIM
  const int N       = out_size / ODIM;          // 50000
  const int NB      = (N + BROWS - 1) / BROWS;  // 391
  const int ntX     = (nnz_x + TILE - 1) / TILE;
  const int ntA     = (nnz_adj + TILE - 1) / TILE;
  const int wwords  = wlen / 2;                 // packed bf16 words

  float* out = (float*)d_out;

  // Workspace layout
  char* p = (char*)d_ws;
  unsigned* bars = (unsigned*)p; p += 256;      // 4 barrier counters (padded)
  int* ghX   = (int*)p;  p += NBMAX * sizeof(int);
  int* ghA   = (int*)p;  p += NBMAX * sizeof(int);
  int* baseX = (int*)p;  p += (NBMAX + 1) * sizeof(int);
  int* baseA = (int*)p;  p += (NBMAX + 1) * sizeof(int);
  int* curX  = (int*)p;  p += NBMAX * sizeof(int);
  int* curA  = (int*)p;  p += NBMAX * sizeof(int);
  int* rpX   = (int*)p;  p += (size_t)(N + 1) * sizeof(int);
  int* rpA   = (int*)p;  p += (size_t)(N + 1) * sizeof(int);
  p = (char*)(((uintptr_t)p + 255) & ~(uintptr_t)255);
  u32* Wbf   = (u32*)p;  p += (size_t)wwords * sizeof(u32);
  p = (char*)(((uintptr_t)p + 255) & ~(uintptr_t)255);
  uint2* bufPX = (uint2*)p; p += (size_t)nnz_x * sizeof(uint2);
  uint2* bufPA = (uint2*)p; p += (size_t)nnz_adj * sizeof(uint2);
  uint2* bufSX = (uint2*)p; p += (size_t)nnz_x * sizeof(uint2);
  uint2* bufSA = (uint2*)p; p += (size_t)nnz_adj * sizeof(uint2);
  size_t need = (size_t)(p - (char*)d_ws);

  const size_t xw_bytes = (size_t)N * 64 * sizeof(u32);
  bool xw_fits = xw_bytes <= ((size_t)nnz_x + nnz_adj) * sizeof(uint2);

  if (ws_size >= need && NB <= NBMAX && xw_fits) {
    u32* xw = (u32*)bufPX;  // aliases ping buffers (dead after prep_all)
    (void)hipMemsetAsync(bars, 0, 4 * sizeof(unsigned), stream);
    prep_all<<<PREP_GRID, PREP_THREADS, 0, stream>>>(
        x_rows, x_cols, x_vals, nnz_x,
        adj_rows, adj_cols, adj_vals, nnz_adj,
        (const float2*)W, Wbf, wwords,
        ghX, ghA, baseX, baseA, curX, curA,
        bufPX, bufPA, bufSX, bufSA, rpX, rpA,
        N, NB, ntX, ntA, bars);
    pull_x<<<(N + 3) / 4, 256, 0, stream>>>(rpX, bufSX, Wbf, xw, N);
    pull_a<<<(N + 3) / 4, 256, 0, stream>>>(rpA, bufSA, xw, (float2*)out, N);
    return;
  }

  // --- Last resort: atomic push (needs only N*ODIM floats).
  {
    float* xwf = (float*)d_ws;
    const size_t out_bytes = (size_t)out_size * sizeof(float);
    (void)hipMemsetAsync(xwf, 0, out_bytes, stream);
    (void)hipMemsetAsync(out, 0, out_bytes, stream);
    spmm_scatter<<<(nnz_x + 1) / 2, 256, 0, stream>>>(x_rows, x_cols, x_vals, W, xwf, nnz_x);
    spmm_scatter<<<(nnz_adj + 1) / 2, 256, 0, stream>>>(adj_rows, adj_cols, adj_vals, xwf, out, nnz_adj);
    relu_inplace<<<2048, 256, 0, stream>>>(out, (long)out_size / 4);
  }
}

// Round 12
// 198.575 us; speedup vs baseline: 1.6166x; 1.6166x over previous
//
#include <hip/hip_runtime.h>

#define ODIM 128          // OUT_DIM
#define BROWS 128         // rows per bucket
#define NBMAX 512         // max buckets (N/128 = 391 for N=50000)
#define TILE 4096         // edges per partition tile
#define CMASK 0x1FFFFu    // low 17 bits of meta = col
#define HISTB 1024        // hist blocks in fused hist+conv kernel
#define CONVB 512         // conv blocks in fused hist+conv kernel

typedef unsigned u32;
typedef unsigned long long u64;

__device__ inline unsigned f2bf(float x) {  // fp32 -> bf16 bits, RNE
  unsigned u = __float_as_uint(x);
  return (u + 0x7fffu + ((u >> 16) & 1u)) >> 16;
}

// ---- fused: bucket histogram (blocks < HISTB) + W->bf16 convert (rest) ----

__global__ __launch_bounds__(256) void hist_conv(
    const int* __restrict__ xr, int nx, const int* __restrict__ ar, int na,
    int* __restrict__ ghX, int* __restrict__ ghA,
    const float2* __restrict__ W2, u32* __restrict__ Wbf, int wwords) {
  __shared__ int lh[2 * NBMAX];
  if ((int)blockIdx.x >= HISTB) {
    // conv part
    int i = (blockIdx.x - HISTB) * 256 + threadIdx.x;
    int stride = CONVB * 256;
    for (; i < wwords; i += stride) {
      float2 w = W2[i];
      Wbf[i] = f2bf(w.x) | (f2bf(w.y) << 16);
    }
    return;
  }
  for (int i = threadIdx.x; i < 2 * NBMAX; i += 256) lh[i] = 0;
  __syncthreads();
  int total = nx + na;
  for (int i = blockIdx.x * 256 + threadIdx.x; i < total; i += HISTB * 256) {
    if (i < nx) atomicAdd(&lh[xr[i] >> 7], 1);
    else        atomicAdd(&lh[NBMAX + (ar[i - nx] >> 7)], 1);
  }
  __syncthreads();
  for (int b = threadIdx.x; b < NBMAX; b += 256) {
    if (lh[b])         atomicAdd(&ghX[b], lh[b]);
    if (lh[NBMAX + b]) atomicAdd(&ghA[b], lh[NBMAX + b]);
  }
}

// ---------------- bucket scan (block 0: X, block 1: A) ----------------

__global__ __launch_bounds__(NBMAX) void scan_buckets(
    int* __restrict__ ghX, int* __restrict__ baseX, int* __restrict__ curX,
    int* __restrict__ ghA, int* __restrict__ baseA, int* __restrict__ curA,
    int nb) {
  int* gh   = blockIdx.x ? ghA   : ghX;
  int* base = blockIdx.x ? baseA : baseX;
  int* cur  = blockIdx.x ? curA  : curX;
  __shared__ int s[NBMAX];
  int tid = threadIdx.x;
  int v = (tid < nb) ? gh[tid] : 0;
  s[tid] = v;
  __syncthreads();
  for (int off = 1; off < NBMAX; off <<= 1) {
    int t = (tid >= off) ? s[tid - off] : 0;
    __syncthreads();
    s[tid] += t;
    __syncthreads();
  }
  int excl = s[tid] - v;
  if (tid < nb) { base[tid] = excl; cur[tid] = excl; }
  if (tid == NBMAX - 1) base[nb] = s[tid];
}

// ---- pass 1: tile counting-sort into buckets (X and A fused in one grid) ----

__global__ __launch_bounds__(256) void partition_both(
    const int* __restrict__ xr, const int* __restrict__ xc,
    const float* __restrict__ xv, int nx, int ntX,
    int* __restrict__ curX, uint2* __restrict__ outX,
    const int* __restrict__ ar, const int* __restrict__ ac,
    const float* __restrict__ av, int na,
    int* __restrict__ curA, uint2* __restrict__ outA) {
  __shared__ uint2 pay[TILE];            // 32KB packed (meta, val)
  __shared__ unsigned short bkt[TILE];   // 8KB
  __shared__ unsigned short perm[TILE];  // 8KB
  __shared__ int hist[NBMAX];
  __shared__ int scn[NBMAX];
  __shared__ int cur[NBMAX];
  __shared__ int gbase[NBMAX];
  __shared__ int part[256];

  const int* rows; const int* cols; const float* vals;
  int nnz; int* gcur; uint2* outbuf; int tile;
  if ((int)blockIdx.x < ntX) {
    rows = xr; cols = xc; vals = xv; nnz = nx; gcur = curX; outbuf = outX;
    tile = blockIdx.x;
  } else {
    rows = ar; cols = ac; vals = av; nnz = na; gcur = curA; outbuf = outA;
    tile = blockIdx.x - ntX;
  }

  int tid = threadIdx.x;
  int tbase = tile * TILE;
  int cnt = nnz - tbase; if (cnt > TILE) cnt = TILE;

  for (int b = tid; b < NBMAX; b += 256) hist[b] = 0;
  __syncthreads();

  // load + local hist
  for (int j = tid; j < cnt; j += 256) {
    int r = rows[tbase + j];
    int c = cols[tbase + j];
    float v = vals[tbase + j];
    unsigned b = (unsigned)r >> 7;
    bkt[j] = (unsigned short)b;
    pay[j] = make_uint2(((unsigned)(r & 127) << 17) | (unsigned)c, __float_as_uint(v));
    atomicAdd(&hist[b], 1);
  }
  __syncthreads();

  // exclusive scan of hist[0..NBMAX) with 256 threads (2 entries each)
  int h0 = hist[2 * tid], h1 = hist[2 * tid + 1];
  int psum = h0 + h1;
  part[tid] = psum;
  __syncthreads();
  for (int off = 1; off < 256; off <<= 1) {
    int t = (tid >= off) ? part[tid - off] : 0;
    __syncthreads();
    part[tid] += t;
    __syncthreads();
  }
  int excl = part[tid] - psum;
  scn[2 * tid] = excl;     scn[2 * tid + 1] = excl + h0;
  cur[2 * tid] = excl;     cur[2 * tid + 1] = excl + h0;
  __syncthreads();

  // place: perm[sorted_pos] = tile idx
  for (int j = tid; j < cnt; j += 256) {
    int pos = atomicAdd(&cur[bkt[j]], 1);
    perm[pos] = (unsigned short)j;
  }
  // reserve global ranges per bucket
  for (int b = tid; b < NBMAX; b += 256) {
    int c = hist[b];
    if (c) gbase[b] = atomicAdd(&gcur[b], c);
  }
  __syncthreads();

  // write out: consecutive sorted positions -> consecutive global slots
  for (int p = tid; p < cnt; p += 256) {
    int j = perm[p];
    int b = bkt[j];
    outbuf[gbase[b] + (p - scn[b])] = pay[j];
  }
}

// ---- pass 2: per-bucket exact row sort + rowptr (X and A fused) ----

__global__ __launch_bounds__(256) void bucket_sort_both(
    int nbX,
    const int* __restrict__ baseX, const uint2* __restrict__ binX,
    uint2* __restrict__ boutX, int* __restrict__ rpX,
    const int* __restrict__ baseA, const uint2* __restrict__ binA,
    uint2* __restrict__ boutA, int* __restrict__ rpA, int N) {
  __shared__ int hist[BROWS], scn[BROWS], cur[BROWS];
  const int* base; const uint2* bufin; uint2* bufout; int* rowptr; int b;
  if ((int)blockIdx.x < nbX) {
    base = baseX; bufin = binX; bufout = boutX; rowptr = rpX; b = blockIdx.x;
  } else {
    base = baseA; bufin = binA; bufout = boutA; rowptr = rpA; b = blockIdx.x - nbX;
  }
  int tid = threadIdx.x;
  int e0 = base[b], ecnt = base[b + 1] - e0;

  if (tid < BROWS) hist[tid] = 0;
  __syncthreads();
  for (int j = tid; j < ecnt; j += 256)
    atomicAdd(&hist[bufin[e0 + j].x >> 17], 1);
  __syncthreads();

  int v = (tid < BROWS) ? hist[tid] : 0;
  if (tid < BROWS) scn[tid] = v;
  __syncthreads();
  for (int off = 1; off < BROWS; off <<= 1) {
    int t = (tid < BROWS && tid >= off) ? scn[tid - off] : 0;
    __syncthreads();
    if (tid < BROWS) scn[tid] += t;
    __syncthreads();
  }
  if (tid < BROWS) {
    int excl = scn[tid] - v;
    cur[tid] = excl;
    int node = b * BROWS + tid;
    if (node <= N) rowptr[node] = e0 + excl;
  }
  __syncthreads();

  for (int j = tid; j < ecnt; j += 256) {
    uint2 e = bufin[e0 + j];
    int pos = atomicAdd(&cur[e.x >> 17], 1);
    bufout[e0 + pos] = e;
  }
}

// ---------------- pulls (wave per row, register accumulate, 8-deep) ---------
// B word l of a row = bf16(dim 2l) | bf16(dim 2l+1)<<16.
// cv edge stream is read with NONTEMPORAL loads (don't pollute L2 — keep the
// gathered table (Wbf / xw) resident); out is written nontemporal.

__global__ __launch_bounds__(256) void pull_x(
    const int* __restrict__ rowptr, const uint2* __restrict__ cv,
    const u32* __restrict__ Wbf, unsigned* __restrict__ xw, int nrows) {
  int lane = threadIdx.x & 63;
  int r = blockIdx.x * 4 + (threadIdx.x >> 6);
  if (r >= nrows) return;
  int e = rowptr[r], end = rowptr[r + 1];
  const u64* cv8 = (const u64*)cv;
  float acc0[8], acc1[8];
#pragma unroll
  for (int u = 0; u < 8; ++u) { acc0[u] = 0.f; acc1[u] = 0.f; }
  for (; e + 7 < end; e += 8) {
    u64 pk[8]; unsigned xg[8];
#pragma unroll
    for (int u = 0; u < 8; ++u) pk[u] = __builtin_nontemporal_load(cv8 + e + u);
#pragma unroll
    for (int u = 0; u < 8; ++u)
      xg[u] = Wbf[(size_t)((unsigned)pk[u] & CMASK) * 64 + lane];
#pragma unroll
    for (int u = 0; u < 8; ++u) {
      float v = __uint_as_float((unsigned)(pk[u] >> 32));
      acc0[u] += v * __uint_as_float(xg[u] << 16);
      acc1[u] += v * __uint_as_float(xg[u] & 0xffff0000u);
    }
  }
  for (; e < end; ++e) {
    u64 pk = __builtin_nontemporal_load(cv8 + e);
    unsigned ua = Wbf[(size_t)((unsigned)pk & CMASK) * 64 + lane];
    float va = __uint_as_float((unsigned)(pk >> 32));
    acc0[0] += va * __uint_as_float(ua << 16);
    acc1[0] += va * __uint_as_float(ua & 0xffff0000u);
  }
  float o0 = ((acc0[0] + acc0[1]) + (acc0[2] + acc0[3])) +
             ((acc0[4] + acc0[5]) + (acc0[6] + acc0[7]));
  float o1 = ((acc1[0] + acc1[1]) + (acc1[2] + acc1[3])) +
             ((acc1[4] + acc1[5]) + (acc1[6] + acc1[7]));
  xw[(size_t)r * 64 + lane] = f2bf(o0) | (f2bf(o1) << 16);
}

__global__ __launch_bounds__(256) void pull_a(
    const int* __restrict__ rowptr, const uint2* __restrict__ cv,
    const unsigned* __restrict__ xw, float2* __restrict__ out, int nrows) {
  int lane = threadIdx.x & 63;
  int r = blockIdx.x * 4 + (threadIdx.x >> 6);
  if (r >= nrows) return;
  int e = rowptr[r], end = rowptr[r + 1];
  const u64* cv8 = (const u64*)cv;
  float acc0[8], acc1[8];
#pragma unroll
  for (int u = 0; u < 8; ++u) { acc0[u] = 0.f; acc1[u] = 0.f; }
  for (; e + 7 < end; e += 8) {
    u64 pk[8]; unsigned xg[8];
#pragma unroll
    for (int u = 0; u < 8; ++u) pk[u] = __builtin_nontemporal_load(cv8 + e + u);
#pragma unroll
    for (int u = 0; u < 8; ++u)
      xg[u] = xw[(size_t)((unsigned)pk[u] & CMASK) * 64 + lane];
#pragma unroll
    for (int u = 0; u < 8; ++u) {
      float v = __uint_as_float((unsigned)(pk[u] >> 32));
      acc0[u] += v * __uint_as_float(xg[u] << 16);
      acc1[u] += v * __uint_as_float(xg[u] & 0xffff0000u);
    }
  }
  for (; e < end; ++e) {
    u64 pk = __builtin_nontemporal_load(cv8 + e);
    unsigned ua = xw[(size_t)((unsigned)pk & CMASK) * 64 + lane];
    float va = __uint_as_float((unsigned)(pk >> 32));
    acc0[0] += va * __uint_as_float(ua << 16);
    acc1[0] += va * __uint_as_float(ua & 0xffff0000u);
  }
  float o0 = ((acc0[0] + acc0[1]) + (acc0[2] + acc0[3])) +
             ((acc0[4] + acc0[5]) + (acc0[6] + acc0[7]));
  float o1 = ((acc1[0] + acc1[1]) + (acc1[2] + acc1[3])) +
             ((acc1[4] + acc1[5]) + (acc1[6] + acc1[7]));
  u64 ov = (u64)__float_as_uint(fmaxf(o0, 0.f)) |
           ((u64)__float_as_uint(fmaxf(o1, 0.f)) << 32);
  __builtin_nontemporal_store(ov, (u64*)(out + (size_t)r * 64 + lane));
}

// ---------------- fallback (atomic push) ----------------

__global__ __launch_bounds__(256) void spmm_scatter(
    const int* __restrict__ rows, const int* __restrict__ cols,
    const float* __restrict__ vals, const float* __restrict__ B,
    float* __restrict__ out, int nnz) {
  int e = blockIdx.x * 2 + (threadIdx.x >> 7);
  int d = threadIdx.x & (ODIM - 1);
  if (e >= nnz) return;
  atomicAdd(&out[(size_t)rows[e] * ODIM + d],
            vals[e] * B[(size_t)cols[e] * ODIM + d]);
}

__global__ __launch_bounds__(256) void relu_inplace(float* __restrict__ p, long n4) {
  long i = (long)blockIdx.x * blockDim.x + threadIdx.x;
  long stride = (long)gridDim.x * blockDim.x;
  float4* p4 = (float4*)p;
  for (long j = i; j < n4; j += stride) {
    float4 v = p4[j];
    v.x = fmaxf(v.x, 0.f); v.y = fmaxf(v.y, 0.f);
    v.z = fmaxf(v.z, 0.f); v.w = fmaxf(v.w, 0.f);
    p4[j] = v;
  }
}

extern "C" void kernel_launch(void* const* d_in, const int* in_sizes, int n_in,
                              void* d_out, int out_size, void* d_ws, size_t ws_size,
                              hipStream_t stream) {
  const int*   x_rows   = (const int*)d_in[0];
  const int*   x_cols   = (const int*)d_in[1];
  const float* x_vals   = (const float*)d_in[2];
  const int*   adj_rows = (const int*)d_in[3];
  const int*   adj_cols = (const int*)d_in[4];
  const float* adj_vals = (const float*)d_in[5];
  const float* W        = (const float*)d_in[6];

  const int nnz_x   = in_sizes[0];
  const int nnz_adj = in_sizes[3];
  const int wlen    = in_sizes[6];              // IN_DIM * ODIM
  const int N       = out_size / ODIM;          // 50000
  const int NB      = (N + BROWS - 1) / BROWS;  // 391
  const int ntX     = (nnz_x + TILE - 1) / TILE;
  const int ntA     = (nnz_adj + TILE - 1) / TILE;
  const int wwords  = wlen / 2;                 // packed bf16 words

  float* out = (float*)d_out;

  // Common control block
  char* p = (char*)d_ws;
  int* ghX   = (int*)p;  p += NBMAX * sizeof(int);
  int* ghA   = (int*)p;  p += NBMAX * sizeof(int);        // adjacent: one memset
  int* baseX = (int*)p;  p += (NBMAX + 1) * sizeof(int);
  int* baseA = (int*)p;  p += (NBMAX + 1) * sizeof(int);
  int* curX  = (int*)p;  p += NBMAX * sizeof(int);
  int* curA  = (int*)p;  p += NBMAX * sizeof(int);
  int* rpX   = (int*)p;  p += (size_t)(N + 1) * sizeof(int);
  int* rpA   = (int*)p;  p += (size_t)(N + 1) * sizeof(int);
  p = (char*)(((uintptr_t)p + 255) & ~(uintptr_t)255);
  u32* Wbf   = (u32*)p;  p += (size_t)wwords * sizeof(u32);
  p = (char*)(((uintptr_t)p + 255) & ~(uintptr_t)255);
  char* bufs = p;

  const size_t xw_bytes = (size_t)N * 64 * sizeof(u32);

  // --- Fused layout: separate ping buffers for X and A (one partition launch).
  // xw aliases bufPX..bufPA (dead after bucket_sort_both).
  {
    char* q = bufs;
    uint2* bufPX = (uint2*)q; q += (size_t)nnz_x * sizeof(uint2);
    uint2* bufPA = (uint2*)q; q += (size_t)nnz_adj * sizeof(uint2);
    uint2* bufSX = (uint2*)q; q += (size_t)nnz_x * sizeof(uint2);
    uint2* bufSA = (uint2*)q; q += (size_t)nnz_adj * sizeof(uint2);
    size_t need = (size_t)(q - (char*)d_ws);
    bool xw_fits = xw_bytes <= ((size_t)nnz_x + nnz_adj) * sizeof(uint2);
    if (ws_size >= need && NB <= NBMAX && xw_fits) {
      u32* xw = (u32*)bufPX;
      (void)hipMemsetAsync(ghX, 0, 2 * NBMAX * sizeof(int), stream);
      hist_conv<<<HISTB + CONVB, 256, 0, stream>>>(
          x_rows, nnz_x, adj_rows, nnz_adj, ghX, ghA,
          (const float2*)W, Wbf, wwords);
      scan_buckets<<<2, NBMAX, 0, stream>>>(ghX, baseX, curX, ghA, baseA, curA, NB);
      partition_both<<<ntX + ntA, 256, 0, stream>>>(
          x_rows, x_cols, x_vals, nnz_x, ntX, curX, bufPX,
          adj_rows, adj_cols, adj_vals, nnz_adj, curA, bufPA);
      bucket_sort_both<<<2 * NB, 256, 0, stream>>>(
          NB, baseX, bufPX, bufSX, rpX, baseA, bufPA, bufSA, rpA, N);
      pull_x<<<(N + 3) / 4, 256, 0, stream>>>(rpX, bufSX, Wbf, xw, N);
      pull_a<<<(N + 3) / 4, 256, 0, stream>>>(rpA, bufSA, xw, (float2*)out, N);
      return;
    }
  }

  // --- Sequential layout (shared ping buffer) if ws smaller.
  {
    size_t bufP_elems = (size_t)(nnz_x > nnz_adj ? nnz_x : nnz_adj);
    if (bufP_elems * sizeof(uint2) < xw_bytes)
      bufP_elems = (xw_bytes + sizeof(uint2) - 1) / sizeof(uint2);
    char* q = bufs;
    uint2* bufP  = (uint2*)q; q += bufP_elems * sizeof(uint2);
    uint2* bufSX = (uint2*)q; q += (size_t)nnz_x * sizeof(uint2);
    uint2* bufSA = (uint2*)q; q += (size_t)nnz_adj * sizeof(uint2);
    size_t need = (size_t)(q - (char*)d_ws);
    if (ws_size >= need && NB <= NBMAX) {
      u32* xw = (u32*)bufP;
      (void)hipMemsetAsync(ghX, 0, 2 * NBMAX * sizeof(int), stream);
      hist_conv<<<HISTB + CONVB, 256, 0, stream>>>(
          x_rows, nnz_x, adj_rows, nnz_adj, ghX, ghA,
          (const float2*)W, Wbf, wwords);
      scan_buckets<<<2, NBMAX, 0, stream>>>(ghX, baseX, curX, ghA, baseA, curA, NB);
      partition_both<<<ntX, 256, 0, stream>>>(
          x_rows, x_cols, x_vals, nnz_x, ntX, curX, bufP,
          adj_rows, adj_cols, adj_vals, nnz_adj, curA, bufP);
      bucket_sort_both<<<NB, 256, 0, stream>>>(
          NB, baseX, bufP, bufSX, rpX, baseA, bufP, bufSA, rpA, N);
      partition_both<<<ntA, 256, 0, stream>>>(
          x_rows, x_cols, x_vals, nnz_x, 0, curX, bufP,
          adj_rows, adj_cols, adj_vals, nnz_adj, curA, bufP);
      bucket_sort_both<<<NB, 256, 0, stream>>>(
          0, baseX, bufP, bufSX, rpX, baseA, bufP, bufSA, rpA, N);
      pull_x<<<(N + 3) / 4, 256, 0, stream>>>(rpX, bufSX, Wbf, xw, N);
      pull_a<<<(N + 3) / 4, 256, 0, stream>>>(rpA, bufSA, xw, (float2*)out, N);
      return;
    }
  }

  // --- Last resort: atomic push (needs only N*ODIM floats).
  {
    float* xwf = (float*)d_ws;
    const size_t out_bytes = (size_t)out_size * sizeof(float);
    (void)hipMemsetAsync(xwf, 0, out_bytes, stream);
    (void)hipMemsetAsync(out, 0, out_bytes, stream);
    spmm_scatter<<<(nnz_x + 1) / 2, 256, 0, stream>>>(x_rows, x_cols, x_vals, W, xwf, nnz_x);
    spmm_scatter<<<(nnz_adj + 1) / 2, 256, 0, stream>>>(adj_rows, adj_cols, adj_vals, xwf, out, nnz_adj);
    relu_inplace<<<2048, 256, 0, stream>>>(out, (long)out_size / 4);
  }
}

// Round 13
// 185.102 us; speedup vs baseline: 1.7343x; 1.0728x over previous
//
#include <hip/hip_runtime.h>

#define ODIM 128          // OUT_DIM
#define BROWS 128         // rows per bucket
#define NBMAX 512         // max buckets (N/128 = 391 for N=50000)
#define TILE 4096         // edges per partition tile
#define CH 4608           // edges per LDS chunk in fused sort+pull
#define CMASK 0x1FFFFu    // low 17 bits of meta = col
#define HISTB 1024        // hist blocks in fused hist+conv kernel
#define CONVB 512         // conv blocks in fused hist+conv kernel

typedef unsigned u32;
typedef unsigned long long u64;

__device__ inline unsigned f2bf(float x) {  // fp32 -> bf16 bits, RNE
  unsigned u = __float_as_uint(x);
  return (u + 0x7fffu + ((u >> 16) & 1u)) >> 16;
}

// ---- fused: bucket histogram (blocks < HISTB) + W->bf16 convert (rest) ----

__global__ __launch_bounds__(256) void hist_conv(
    const int* __restrict__ xr, int nx, const int* __restrict__ ar, int na,
    int* __restrict__ ghX, int* __restrict__ ghA,
    const float2* __restrict__ W2, u32* __restrict__ Wbf, int wwords) {
  __shared__ int lh[2 * NBMAX];
  if ((int)blockIdx.x >= HISTB) {
    int i = (blockIdx.x - HISTB) * 256 + threadIdx.x;
    int stride = CONVB * 256;
    for (; i < wwords; i += stride) {
      float2 w = W2[i];
      Wbf[i] = f2bf(w.x) | (f2bf(w.y) << 16);
    }
    return;
  }
  for (int i = threadIdx.x; i < 2 * NBMAX; i += 256) lh[i] = 0;
  __syncthreads();
  int total = nx + na;
  for (int i = blockIdx.x * 256 + threadIdx.x; i < total; i += HISTB * 256) {
    if (i < nx) atomicAdd(&lh[xr[i] >> 7], 1);
    else        atomicAdd(&lh[NBMAX + (ar[i - nx] >> 7)], 1);
  }
  __syncthreads();
  for (int b = threadIdx.x; b < NBMAX; b += 256) {
    if (lh[b])         atomicAdd(&ghX[b], lh[b]);
    if (lh[NBMAX + b]) atomicAdd(&ghA[b], lh[NBMAX + b]);
  }
}

// ---------------- bucket scan (block 0: X, block 1: A) ----------------

__global__ __launch_bounds__(NBMAX) void scan_buckets(
    int* __restrict__ ghX, int* __restrict__ baseX, int* __restrict__ curX,
    int* __restrict__ ghA, int* __restrict__ baseA, int* __restrict__ curA,
    int nb) {
  int* gh   = blockIdx.x ? ghA   : ghX;
  int* base = blockIdx.x ? baseA : baseX;
  int* cur  = blockIdx.x ? curA  : curX;
  __shared__ int s[NBMAX];
  int tid = threadIdx.x;
  int v = (tid < nb) ? gh[tid] : 0;
  s[tid] = v;
  __syncthreads();
  for (int off = 1; off < NBMAX; off <<= 1) {
    int t = (tid >= off) ? s[tid - off] : 0;
    __syncthreads();
    s[tid] += t;
    __syncthreads();
  }
  int excl = s[tid] - v;
  if (tid < nb) { base[tid] = excl; cur[tid] = excl; }
  if (tid == NBMAX - 1) base[nb] = s[tid];
}

// ---- pass 1: tile counting-sort into buckets (X and A fused in one grid) ----

__global__ __launch_bounds__(256) void partition_both(
    const int* __restrict__ xr, const int* __restrict__ xc,
    const float* __restrict__ xv, int nx, int ntX,
    int* __restrict__ curX, uint2* __restrict__ outX,
    const int* __restrict__ ar, const int* __restrict__ ac,
    const float* __restrict__ av, int na,
    int* __restrict__ curA, uint2* __restrict__ outA) {
  __shared__ uint2 pay[TILE];            // 32KB packed (meta, val)
  __shared__ unsigned short bkt[TILE];   // 8KB
  __shared__ unsigned short perm[TILE];  // 8KB
  __shared__ int hist[NBMAX];
  __shared__ int scn[NBMAX];
  __shared__ int cur[NBMAX];
  __shared__ int gbase[NBMAX];
  __shared__ int part[256];

  const int* rows; const int* cols; const float* vals;
  int nnz; int* gcur; uint2* outbuf; int tile;
  if ((int)blockIdx.x < ntX) {
    rows = xr; cols = xc; vals = xv; nnz = nx; gcur = curX; outbuf = outX;
    tile = blockIdx.x;
  } else {
    rows = ar; cols = ac; vals = av; nnz = na; gcur = curA; outbuf = outA;
    tile = blockIdx.x - ntX;
  }

  int tid = threadIdx.x;
  int tbase = tile * TILE;
  int cnt = nnz - tbase; if (cnt > TILE) cnt = TILE;

  for (int b = tid; b < NBMAX; b += 256) hist[b] = 0;
  __syncthreads();

  for (int j = tid; j < cnt; j += 256) {
    int r = rows[tbase + j];
    int c = cols[tbase + j];
    float v = vals[tbase + j];
    unsigned b = (unsigned)r >> 7;
    bkt[j] = (unsigned short)b;
    pay[j] = make_uint2(((unsigned)(r & 127) << 17) | (unsigned)c, __float_as_uint(v));
    atomicAdd(&hist[b], 1);
  }
  __syncthreads();

  int h0 = hist[2 * tid], h1 = hist[2 * tid + 1];
  int psum = h0 + h1;
  part[tid] = psum;
  __syncthreads();
  for (int off = 1; off < 256; off <<= 1) {
    int t = (tid >= off) ? part[tid - off] : 0;
    __syncthreads();
    part[tid] += t;
    __syncthreads();
  }
  int excl = part[tid] - psum;
  scn[2 * tid] = excl;     scn[2 * tid + 1] = excl + h0;
  cur[2 * tid] = excl;     cur[2 * tid + 1] = excl + h0;
  __syncthreads();

  for (int j = tid; j < cnt; j += 256) {
    int pos = atomicAdd(&cur[bkt[j]], 1);
    perm[pos] = (unsigned short)j;
  }
  for (int b = tid; b < NBMAX; b += 256) {
    int c = hist[b];
    if (c) gbase[b] = atomicAdd(&gcur[b], c);
  }
  __syncthreads();

  for (int p = tid; p < cnt; p += 256) {
    int j = perm[p];
    int b = bkt[j];
    outbuf[gbase[b] + (p - scn[b])] = pay[j];
  }
}

// ---- fused per-bucket LDS sort + pull (one block per bucket, 8 waves) ----
// Chunk the bucket's edges into LDS, counting-sort by row via perm indices,
// then wave w gathers rows [w*16, w*16+16) with 8-deep MLP, accumulating in
// statically-indexed registers. Writes final output directly.

template <bool ISX>
__global__ __launch_bounds__(512) void fused_sort_pull(
    const int* __restrict__ base, const uint2* __restrict__ bufP,
    const u32* __restrict__ table,   // Wbf (X) or xw (A)
    u32* __restrict__ xwout,         // X: xw
    float2* __restrict__ aout,       // A: final output
    int N) {
  __shared__ uint2 pay[CH];                 // 36864B
  __shared__ unsigned short perm[CH];       // 9216B
  __shared__ int hist[BROWS], startb[BROWS], cur[BROWS];  // 1536B
  int tid = threadIdx.x;
  int lane = tid & 63;
  int w = tid >> 6;  // wave 0..7
  int b = blockIdx.x;
  int e0 = base[b], etot = base[b + 1] - e0;

  float acc0[16], acc1[16];
#pragma unroll
  for (int i = 0; i < 16; ++i) { acc0[i] = 0.f; acc1[i] = 0.f; }

  for (int coff = 0; coff < etot; coff += CH) {
    int cnt = etot - coff; if (cnt > CH) cnt = CH;
    __syncthreads();  // protect LDS from previous chunk's readers
    if (tid < BROWS) hist[tid] = 0;
    __syncthreads();
    for (int j = tid; j < cnt; j += 512) {
      uint2 e = bufP[e0 + coff + j];
      pay[j] = e;
      atomicAdd(&hist[e.x >> 17], 1);
    }
    __syncthreads();
    // inclusive scan over 128 bins (whole-block barriers)
    int v = (tid < BROWS) ? hist[tid] : 0;
    if (tid < BROWS) startb[tid] = v;
    __syncthreads();
    for (int off = 1; off < BROWS; off <<= 1) {
      int t = (tid < BROWS && tid >= off) ? startb[tid - off] : 0;
      __syncthreads();
      if (tid < BROWS) startb[tid] += t;
      __syncthreads();
    }
    if (tid < BROWS) {
      int excl = startb[tid] - v;
      startb[tid] = excl;
      cur[tid] = excl;
    }
    __syncthreads();
    for (int j = tid; j < cnt; j += 512) {
      int pos = atomicAdd(&cur[pay[j].x >> 17], 1);
      perm[pos] = (unsigned short)j;
    }
    __syncthreads();
    // gather + accumulate: wave w owns rows [w*16, w*16+16)
#pragma unroll
    for (int rr = 0; rr < 16; ++rr) {
      int r = w * 16 + rr;
      int e = startb[r];
      int eend = e + hist[r];
      for (; e + 7 < eend; e += 8) {
        unsigned mt[8]; float vv[8]; unsigned xg[8];
#pragma unroll
        for (int u = 0; u < 8; ++u) {
          uint2 t = pay[perm[e + u]];
          mt[u] = t.x; vv[u] = __uint_as_float(t.y);
        }
#pragma unroll
        for (int u = 0; u < 8; ++u)
          xg[u] = table[(size_t)(mt[u] & CMASK) * 64 + lane];
#pragma unroll
        for (int u = 0; u < 8; ++u) {
          acc0[rr] += vv[u] * __uint_as_float(xg[u] << 16);
          acc1[rr] += vv[u] * __uint_as_float(xg[u] & 0xffff0000u);
        }
      }
      for (; e < eend; ++e) {
        uint2 t = pay[perm[e]];
        unsigned ua = table[(size_t)(t.x & CMASK) * 64 + lane];
        float va = __uint_as_float(t.y);
        acc0[rr] += va * __uint_as_float(ua << 16);
        acc1[rr] += va * __uint_as_float(ua & 0xffff0000u);
      }
    }
  }

  // write output
#pragma unroll
  for (int rr = 0; rr < 16; ++rr) {
    int node = b * BROWS + w * 16 + rr;
    if (node < N) {
      if (ISX) {
        xwout[(size_t)node * 64 + lane] = f2bf(acc0[rr]) | (f2bf(acc1[rr]) << 16);
      } else {
        aout[(size_t)node * 64 + lane] =
            make_float2(fmaxf(acc0[rr], 0.f), fmaxf(acc1[rr], 0.f));
      }
    }
  }
}

// ---------------- fallback (atomic push) ----------------

__global__ __launch_bounds__(256) void spmm_scatter(
    const int* __restrict__ rows, const int* __restrict__ cols,
    const float* __restrict__ vals, const float* __restrict__ B,
    float* __restrict__ out, int nnz) {
  int e = blockIdx.x * 2 + (threadIdx.x >> 7);
  int d = threadIdx.x & (ODIM - 1);
  if (e >= nnz) return;
  atomicAdd(&out[(size_t)rows[e] * ODIM + d],
            vals[e] * B[(size_t)cols[e] * ODIM + d]);
}

__global__ __launch_bounds__(256) void relu_inplace(float* __restrict__ p, long n4) {
  long i = (long)blockIdx.x * blockDim.x + threadIdx.x;
  long stride = (long)gridDim.x * blockDim.x;
  float4* p4 = (float4*)p;
  for (long j = i; j < n4; j += stride) {
    float4 v = p4[j];
    v.x = fmaxf(v.x, 0.f); v.y = fmaxf(v.y, 0.f);
    v.z = fmaxf(v.z, 0.f); v.w = fmaxf(v.w, 0.f);
    p4[j] = v;
  }
}

extern "C" void kernel_launch(void* const* d_in, const int* in_sizes, int n_in,
                              void* d_out, int out_size, void* d_ws, size_t ws_size,
                              hipStream_t stream) {
  const int*   x_rows   = (const int*)d_in[0];
  const int*   x_cols   = (const int*)d_in[1];
  const float* x_vals   = (const float*)d_in[2];
  const int*   adj_rows = (const int*)d_in[3];
  const int*   adj_cols = (const int*)d_in[4];
  const float* adj_vals = (const float*)d_in[5];
  const float* W        = (const float*)d_in[6];

  const int nnz_x   = in_sizes[0];
  const int nnz_adj = in_sizes[3];
  const int wlen    = in_sizes[6];              // IN_DIM * ODIM
  const int N       = out_size / ODIM;          // 50000
  const int NB      = (N + BROWS - 1) / BROWS;  // 391
  const int ntX     = (nnz_x + TILE - 1) / TILE;
  const int ntA     = (nnz_adj + TILE - 1) / TILE;
  const int wwords  = wlen / 2;                 // packed bf16 words

  float* out = (float*)d_out;

  // Workspace layout
  char* p = (char*)d_ws;
  int* ghX   = (int*)p;  p += NBMAX * sizeof(int);
  int* ghA   = (int*)p;  p += NBMAX * sizeof(int);        // adjacent: one memset
  int* baseX = (int*)p;  p += (NBMAX + 1) * sizeof(int);
  int* baseA = (int*)p;  p += (NBMAX + 1) * sizeof(int);
  int* curX  = (int*)p;  p += NBMAX * sizeof(int);
  int* curA  = (int*)p;  p += NBMAX * sizeof(int);
  p = (char*)(((uintptr_t)p + 255) & ~(uintptr_t)255);
  u32* Wbf   = (u32*)p;  p += (size_t)wwords * sizeof(u32);
  p = (char*)(((uintptr_t)p + 255) & ~(uintptr_t)255);
  u32* xw    = (u32*)p;  p += (size_t)N * 64 * sizeof(u32);
  p = (char*)(((uintptr_t)p + 255) & ~(uintptr_t)255);
  uint2* bufPX = (uint2*)p; p += (size_t)nnz_x * sizeof(uint2);
  uint2* bufPA = (uint2*)p; p += (size_t)nnz_adj * sizeof(uint2);
  size_t need = (size_t)(p - (char*)d_ws);

  if (ws_size >= need && NB <= NBMAX) {
    (void)hipMemsetAsync(ghX, 0, 2 * NBMAX * sizeof(int), stream);
    hist_conv<<<HISTB + CONVB, 256, 0, stream>>>(
        x_rows, nnz_x, adj_rows, nnz_adj, ghX, ghA,
        (const float2*)W, Wbf, wwords);
    scan_buckets<<<2, NBMAX, 0, stream>>>(ghX, baseX, curX, ghA, baseA, curA, NB);
    partition_both<<<ntX + ntA, 256, 0, stream>>>(
        x_rows, x_cols, x_vals, nnz_x, ntX, curX, bufPX,
        adj_rows, adj_cols, adj_vals, nnz_adj, curA, bufPA);
    // Step 1: xw = X @ W (sort+pull fused per bucket)
    fused_sort_pull<true><<<NB, 512, 0, stream>>>(baseX, bufPX, Wbf, xw, nullptr, N);
    // Step 2: out = relu(A @ xw)
    fused_sort_pull<false><<<NB, 512, 0, stream>>>(baseA, bufPA, xw, nullptr, (float2*)out, N);
    return;
  }

  // --- Last resort: atomic push (needs only N*ODIM floats).
  {
    float* xwf = (float*)d_ws;
    const size_t out_bytes = (size_t)out_size * sizeof(float);
    (void)hipMemsetAsync(xwf, 0, out_bytes, stream);
    (void)hipMemsetAsync(out, 0, out_bytes, stream);
    spmm_scatter<<<(nnz_x + 1) / 2, 256, 0, stream>>>(x_rows, x_cols, x_vals, W, xwf, nnz_x);
    spmm_scatter<<<(nnz_adj + 1) / 2, 256, 0, stream>>>(adj_rows, adj_cols, adj_vals, xwf, out, nnz_adj);
    relu_inplace<<<2048, 256, 0, stream>>>(out, (long)out_size / 4);
  }
}

// Round 14
// 181.371 us; speedup vs baseline: 1.7699x; 1.0206x over previous
//
#include <hip/hip_runtime.h>

#define ODIM 128          // OUT_DIM
#define BROWS 128         // rows per bucket
#define NBMAX 512         // max buckets (N/128 = 391 for N=50000)
#define TILE 2048         // edges per partition tile (29KB LDS -> 4-5 blocks/CU)
#define CMASK 0x1FFFFu    // low 17 bits of meta = col
#define HISTB 1024        // hist blocks in fused hist+conv kernel
#define CONVB 512         // conv blocks in fused hist+conv kernel

typedef unsigned u32;

__device__ inline unsigned f2bf(float x) {  // fp32 -> bf16 bits, RNE
  unsigned u = __float_as_uint(x);
  return (u + 0x7fffu + ((u >> 16) & 1u)) >> 16;
}

// ---- fused: bucket histogram (blocks < HISTB) + W->bf16 convert (rest) ----

__global__ __launch_bounds__(256) void hist_conv(
    const int* __restrict__ xr, int nx, const int* __restrict__ ar, int na,
    int* __restrict__ ghX, int* __restrict__ ghA,
    const float2* __restrict__ W2, u32* __restrict__ Wbf, int wwords) {
  __shared__ int lh[2 * NBMAX];
  if ((int)blockIdx.x >= HISTB) {
    int i = (blockIdx.x - HISTB) * 256 + threadIdx.x;
    int stride = CONVB * 256;
    for (; i < wwords; i += stride) {
      float2 w = W2[i];
      Wbf[i] = f2bf(w.x) | (f2bf(w.y) << 16);
    }
    return;
  }
  for (int i = threadIdx.x; i < 2 * NBMAX; i += 256) lh[i] = 0;
  __syncthreads();
  int total = nx + na;
  for (int i = blockIdx.x * 256 + threadIdx.x; i < total; i += HISTB * 256) {
    if (i < nx) atomicAdd(&lh[xr[i] >> 7], 1);
    else        atomicAdd(&lh[NBMAX + (ar[i - nx] >> 7)], 1);
  }
  __syncthreads();
  for (int b = threadIdx.x; b < NBMAX; b += 256) {
    if (lh[b])         atomicAdd(&ghX[b], lh[b]);
    if (lh[NBMAX + b]) atomicAdd(&ghA[b], lh[NBMAX + b]);
  }
}

// ---------------- bucket scan (block 0: X, block 1: A) ----------------

__global__ __launch_bounds__(NBMAX) void scan_buckets(
    int* __restrict__ ghX, int* __restrict__ baseX, int* __restrict__ curX,
    int* __restrict__ ghA, int* __restrict__ baseA, int* __restrict__ curA,
    int nb) {
  int* gh   = blockIdx.x ? ghA   : ghX;
  int* base = blockIdx.x ? baseA : baseX;
  int* cur  = blockIdx.x ? curA  : curX;
  __shared__ int s[NBMAX];
  int tid = threadIdx.x;
  int v = (tid < nb) ? gh[tid] : 0;
  s[tid] = v;
  __syncthreads();
  for (int off = 1; off < NBMAX; off <<= 1) {
    int t = (tid >= off) ? s[tid - off] : 0;
    __syncthreads();
    s[tid] += t;
    __syncthreads();
  }
  int excl = s[tid] - v;
  if (tid < nb) { base[tid] = excl; cur[tid] = excl; }
  if (tid == NBMAX - 1) base[nb] = s[tid];
}

// ---- pass 1: tile counting-sort into buckets (X and A fused in one grid) ----

__global__ __launch_bounds__(256) void partition_both(
    const int* __restrict__ xr, const int* __restrict__ xc,
    const float* __restrict__ xv, int nx, int ntX,
    int* __restrict__ curX, uint2* __restrict__ outX,
    const int* __restrict__ ar, const int* __restrict__ ac,
    const float* __restrict__ av, int na,
    int* __restrict__ curA, uint2* __restrict__ outA) {
  __shared__ uint2 pay[TILE];            // 16KB packed (meta, val)
  __shared__ unsigned short bkt[TILE];   // 4KB
  __shared__ unsigned short perm[TILE];  // 4KB
  __shared__ int hist[NBMAX];
  __shared__ int scn[NBMAX];
  __shared__ int cur[NBMAX];
  __shared__ int gbase[NBMAX];
  __shared__ int part[256];

  const int* rows; const int* cols; const float* vals;
  int nnz; int* gcur; uint2* outbuf; int tile;
  if ((int)blockIdx.x < ntX) {
    rows = xr; cols = xc; vals = xv; nnz = nx; gcur = curX; outbuf = outX;
    tile = blockIdx.x;
  } else {
    rows = ar; cols = ac; vals = av; nnz = na; gcur = curA; outbuf = outA;
    tile = blockIdx.x - ntX;
  }

  int tid = threadIdx.x;
  int tbase = tile * TILE;
  int cnt = nnz - tbase; if (cnt > TILE) cnt = TILE;

  for (int b = tid; b < NBMAX; b += 256) hist[b] = 0;
  __syncthreads();

  for (int j = tid; j < cnt; j += 256) {
    int r = rows[tbase + j];
    int c = cols[tbase + j];
    float v = vals[tbase + j];
    unsigned b = (unsigned)r >> 7;
    bkt[j] = (unsigned short)b;
    pay[j] = make_uint2(((unsigned)(r & 127) << 17) | (unsigned)c, __float_as_uint(v));
    atomicAdd(&hist[b], 1);
  }
  __syncthreads();

  int h0 = hist[2 * tid], h1 = hist[2 * tid + 1];
  int psum = h0 + h1;
  part[tid] = psum;
  __syncthreads();
  for (int off = 1; off < 256; off <<= 1) {
    int t = (tid >= off) ? part[tid - off] : 0;
    __syncthreads();
    part[tid] += t;
    __syncthreads();
  }
  int excl = part[tid] - psum;
  scn[2 * tid] = excl;     scn[2 * tid + 1] = excl + h0;
  cur[2 * tid] = excl;     cur[2 * tid + 1] = excl + h0;
  __syncthreads();

  for (int j = tid; j < cnt; j += 256) {
    int pos = atomicAdd(&cur[bkt[j]], 1);
    perm[pos] = (unsigned short)j;
  }
  for (int b = tid; b < NBMAX; b += 256) {
    int c = hist[b];
    if (c) gbase[b] = atomicAdd(&gcur[b], c);
  }
  __syncthreads();

  for (int p = tid; p < cnt; p += 256) {
    int j = perm[p];
    int b = bkt[j];
    outbuf[gbase[b] + (p - scn[b])] = pay[j];
  }
}

// ---- pass 2: per-bucket exact row sort + rowptr (X and A fused) ----

__global__ __launch_bounds__(256) void bucket_sort_both(
    int nbX,
    const int* __restrict__ baseX, const uint2* __restrict__ binX,
    uint2* __restrict__ boutX, int* __restrict__ rpX,
    const int* __restrict__ baseA, const uint2* __restrict__ binA,
    uint2* __restrict__ boutA, int* __restrict__ rpA, int N) {
  __shared__ int hist[BROWS], scn[BROWS], cur[BROWS];
  const int* base; const uint2* bufin; uint2* bufout; int* rowptr; int b;
  if ((int)blockIdx.x < nbX) {
    base = baseX; bufin = binX; bufout = boutX; rowptr = rpX; b = blockIdx.x;
  } else {
    base = baseA; bufin = binA; bufout = boutA; rowptr = rpA; b = blockIdx.x - nbX;
  }
  int tid = threadIdx.x;
  int e0 = base[b], ecnt = base[b + 1] - e0;

  if (tid < BROWS) hist[tid] = 0;
  __syncthreads();
  for (int j = tid; j < ecnt; j += 256)
    atomicAdd(&hist[bufin[e0 + j].x >> 17], 1);
  __syncthreads();

  int v = (tid < BROWS) ? hist[tid] : 0;
  if (tid < BROWS) scn[tid] = v;
  __syncthreads();
  for (int off = 1; off < BROWS; off <<= 1) {
    int t = (tid < BROWS && tid >= off) ? scn[tid - off] : 0;
    __syncthreads();
    if (tid < BROWS) scn[tid] += t;
    __syncthreads();
  }
  if (tid < BROWS) {
    int excl = scn[tid] - v;
    cur[tid] = excl;
    int node = b * BROWS + tid;
    if (node <= N) rowptr[node] = e0 + excl;
  }
  __syncthreads();

  for (int j = tid; j < ecnt; j += 256) {
    uint2 e = bufin[e0 + j];
    int pos = atomicAdd(&cur[e.x >> 17], 1);
    bufout[e0 + pos] = e;
  }
}

// ---------------- pulls (wave per row, register accumulate, 8-deep) ---------
// Table word l of a row = bf16(dim 2l) | bf16(dim 2l+1)<<16.

__global__ __launch_bounds__(256) void pull_x(
    const int* __restrict__ rowptr, const uint2* __restrict__ cv,
    const u32* __restrict__ Wbf, unsigned* __restrict__ xw, int nrows) {
  int lane = threadIdx.x & 63;
  int r = blockIdx.x * 4 + (threadIdx.x >> 6);
  if (r >= nrows) return;
  int e = rowptr[r], end = rowptr[r + 1];
  float acc0[8], acc1[8];
#pragma unroll
  for (int u = 0; u < 8; ++u) { acc0[u] = 0.f; acc1[u] = 0.f; }
  for (; e + 7 < end; e += 8) {
    uint2 ed[8]; unsigned xg[8];
#pragma unroll
    for (int u = 0; u < 8; ++u) ed[u] = cv[e + u];
#pragma unroll
    for (int u = 0; u < 8; ++u)
      xg[u] = Wbf[(size_t)(ed[u].x & CMASK) * 64 + lane];
#pragma unroll
    for (int u = 0; u < 8; ++u) {
      float v = __uint_as_float(ed[u].y);
      acc0[u] += v * __uint_as_float(xg[u] << 16);
      acc1[u] += v * __uint_as_float(xg[u] & 0xffff0000u);
    }
  }
  for (; e + 1 < end; e += 2) {
    uint2 ea = cv[e], eb = cv[e + 1];
    unsigned ua = Wbf[(size_t)(ea.x & CMASK) * 64 + lane];
    unsigned ub = Wbf[(size_t)(eb.x & CMASK) * 64 + lane];
    float va = __uint_as_float(ea.y), vb = __uint_as_float(eb.y);
    acc0[0] += va * __uint_as_float(ua << 16);
    acc1[0] += va * __uint_as_float(ua & 0xffff0000u);
    acc0[1] += vb * __uint_as_float(ub << 16);
    acc1[1] += vb * __uint_as_float(ub & 0xffff0000u);
  }
  if (e < end) {
    uint2 ea = cv[e];
    unsigned ua = Wbf[(size_t)(ea.x & CMASK) * 64 + lane];
    float va = __uint_as_float(ea.y);
    acc0[2] += va * __uint_as_float(ua << 16);
    acc1[2] += va * __uint_as_float(ua & 0xffff0000u);
  }
  float o0 = ((acc0[0] + acc0[1]) + (acc0[2] + acc0[3])) +
             ((acc0[4] + acc0[5]) + (acc0[6] + acc0[7]));
  float o1 = ((acc1[0] + acc1[1]) + (acc1[2] + acc1[3])) +
             ((acc1[4] + acc1[5]) + (acc1[6] + acc1[7]));
  xw[(size_t)r * 64 + lane] = f2bf(o0) | (f2bf(o1) << 16);
}

__global__ __launch_bounds__(256) void pull_a(
    const int* __restrict__ rowptr, const uint2* __restrict__ cv,
    const unsigned* __restrict__ xw, float2* __restrict__ out, int nrows) {
  int lane = threadIdx.x & 63;
  int r = blockIdx.x * 4 + (threadIdx.x >> 6);
  if (r >= nrows) return;
  int e = rowptr[r], end = rowptr[r + 1];
  float acc0[8], acc1[8];
#pragma unroll
  for (int u = 0; u < 8; ++u) { acc0[u] = 0.f; acc1[u] = 0.f; }
  for (; e + 7 < end; e += 8) {
    uint2 ed[8]; unsigned xg[8];
#pragma unroll
    for (int u = 0; u < 8; ++u) ed[u] = cv[e + u];
#pragma unroll
    for (int u = 0; u < 8; ++u)
      xg[u] = xw[(size_t)(ed[u].x & CMASK) * 64 + lane];
#pragma unroll
    for (int u = 0; u < 8; ++u) {
      float v = __uint_as_float(ed[u].y);
      acc0[u] += v * __uint_as_float(xg[u] << 16);
      acc1[u] += v * __uint_as_float(xg[u] & 0xffff0000u);
    }
  }
  for (; e + 1 < end; e += 2) {
    uint2 ea = cv[e], eb = cv[e + 1];
    unsigned ua = xw[(size_t)(ea.x & CMASK) * 64 + lane];
    unsigned ub = xw[(size_t)(eb.x & CMASK) * 64 + lane];
    float va = __uint_as_float(ea.y), vb = __uint_as_float(eb.y);
    acc0[0] += va * __uint_as_float(ua << 16);
    acc1[0] += va * __uint_as_float(ua & 0xffff0000u);
    acc0[1] += vb * __uint_as_float(ub << 16);
    acc1[1] += vb * __uint_as_float(ub & 0xffff0000u);
  }
  if (e < end) {
    uint2 ea = cv[e];
    unsigned ua = xw[(size_t)(ea.x & CMASK) * 64 + lane];
    float va = __uint_as_float(ea.y);
    acc0[2] += va * __uint_as_float(ua << 16);
    acc1[2] += va * __uint_as_float(ua & 0xffff0000u);
  }
  float o0 = ((acc0[0] + acc0[1]) + (acc0[2] + acc0[3])) +
             ((acc0[4] + acc0[5]) + (acc0[6] + acc0[7]));
  float o1 = ((acc1[0] + acc1[1]) + (acc1[2] + acc1[3])) +
             ((acc1[4] + acc1[5]) + (acc1[6] + acc1[7]));
  out[(size_t)r * 64 + lane] = make_float2(fmaxf(o0, 0.f), fmaxf(o1, 0.f));
}

// ---------------- fallback (atomic push) ----------------

__global__ __launch_bounds__(256) void spmm_scatter(
    const int* __restrict__ rows, const int* __restrict__ cols,
    const float* __restrict__ vals, const float* __restrict__ B,
    float* __restrict__ out, int nnz) {
  int e = blockIdx.x * 2 + (threadIdx.x >> 7);
  int d = threadIdx.x & (ODIM - 1);
  if (e >= nnz) return;
  atomicAdd(&out[(size_t)rows[e] * ODIM + d],
            vals[e] * B[(size_t)cols[e] * ODIM + d]);
}

__global__ __launch_bounds__(256) void relu_inplace(float* __restrict__ p, long n4) {
  long i = (long)blockIdx.x * blockDim.x + threadIdx.x;
  long stride = (long)gridDim.x * blockDim.x;
  float4* p4 = (float4*)p;
  for (long j = i; j < n4; j += stride) {
    float4 v = p4[j];
    v.x = fmaxf(v.x, 0.f); v.y = fmaxf(v.y, 0.f);
    v.z = fmaxf(v.z, 0.f); v.w = fmaxf(v.w, 0.f);
    p4[j] = v;
  }
}

extern "C" void kernel_launch(void* const* d_in, const int* in_sizes, int n_in,
                              void* d_out, int out_size, void* d_ws, size_t ws_size,
                              hipStream_t stream) {
  const int*   x_rows   = (const int*)d_in[0];
  const int*   x_cols   = (const int*)d_in[1];
  const float* x_vals   = (const float*)d_in[2];
  const int*   adj_rows = (const int*)d_in[3];
  const int*   adj_cols = (const int*)d_in[4];
  const float* adj_vals = (const float*)d_in[5];
  const float* W        = (const float*)d_in[6];

  const int nnz_x   = in_sizes[0];
  const int nnz_adj = in_sizes[3];
  const int wlen    = in_sizes[6];              // IN_DIM * ODIM
  const int N       = out_size / ODIM;          // 50000
  const int NB      = (N + BROWS - 1) / BROWS;  // 391
  const int ntX     = (nnz_x + TILE - 1) / TILE;
  const int ntA     = (nnz_adj + TILE - 1) / TILE;
  const int wwords  = wlen / 2;                 // packed bf16 words

  float* out = (float*)d_out;

  // Common control block
  char* p = (char*)d_ws;
  int* ghX   = (int*)p;  p += NBMAX * sizeof(int);
  int* ghA   = (int*)p;  p += NBMAX * sizeof(int);        // adjacent: one memset
  int* baseX = (int*)p;  p += (NBMAX + 1) * sizeof(int);
  int* baseA = (int*)p;  p += (NBMAX + 1) * sizeof(int);
  int* curX  = (int*)p;  p += NBMAX * sizeof(int);
  int* curA  = (int*)p;  p += NBMAX * sizeof(int);
  int* rpX   = (int*)p;  p += (size_t)(N + 1) * sizeof(int);
  int* rpA   = (int*)p;  p += (size_t)(N + 1) * sizeof(int);
  p = (char*)(((uintptr_t)p + 255) & ~(uintptr_t)255);
  u32* Wbf   = (u32*)p;  p += (size_t)wwords * sizeof(u32);
  p = (char*)(((uintptr_t)p + 255) & ~(uintptr_t)255);
  char* bufs = p;

  const size_t xw_bytes = (size_t)N * 64 * sizeof(u32);

  // --- Fused layout: separate ping buffers for X and A (one partition launch).
  // xw aliases bufPX..bufPA (dead after bucket_sort_both).
  {
    char* q = bufs;
    uint2* bufPX = (uint2*)q; q += (size_t)nnz_x * sizeof(uint2);
    uint2* bufPA = (uint2*)q; q += (size_t)nnz_adj * sizeof(uint2);
    uint2* bufSX = (uint2*)q; q += (size_t)nnz_x * sizeof(uint2);
    uint2* bufSA = (uint2*)q; q += (size_t)nnz_adj * sizeof(uint2);
    size_t need = (size_t)(q - (char*)d_ws);
    bool xw_fits = xw_bytes <= ((size_t)nnz_x + nnz_adj) * sizeof(uint2);
    if (ws_size >= need && NB <= NBMAX && xw_fits) {
      u32* xw = (u32*)bufPX;
      (void)hipMemsetAsync(ghX, 0, 2 * NBMAX * sizeof(int), stream);
      hist_conv<<<HISTB + CONVB, 256, 0, stream>>>(
          x_rows, nnz_x, adj_rows, nnz_adj, ghX, ghA,
          (const float2*)W, Wbf, wwords);
      scan_buckets<<<2, NBMAX, 0, stream>>>(ghX, baseX, curX, ghA, baseA, curA, NB);
      partition_both<<<ntX + ntA, 256, 0, stream>>>(
          x_rows, x_cols, x_vals, nnz_x, ntX, curX, bufPX,
          adj_rows, adj_cols, adj_vals, nnz_adj, curA, bufPA);
      bucket_sort_both<<<2 * NB, 256, 0, stream>>>(
          NB, baseX, bufPX, bufSX, rpX, baseA, bufPA, bufSA, rpA, N);
      pull_x<<<(N + 3) / 4, 256, 0, stream>>>(rpX, bufSX, Wbf, xw, N);
      pull_a<<<(N + 3) / 4, 256, 0, stream>>>(rpA, bufSA, xw, (float2*)out, N);
      return;
    }
  }

  // --- Sequential layout (shared ping buffer) if ws smaller.
  {
    size_t bufP_elems = (size_t)(nnz_x > nnz_adj ? nnz_x : nnz_adj);
    if (bufP_elems * sizeof(uint2) < xw_bytes)
      bufP_elems = (xw_bytes + sizeof(uint2) - 1) / sizeof(uint2);
    char* q = bufs;
    uint2* bufP  = (uint2*)q; q += bufP_elems * sizeof(uint2);
    uint2* bufSX = (uint2*)q; q += (size_t)nnz_x * sizeof(uint2);
    uint2* bufSA = (uint2*)q; q += (size_t)nnz_adj * sizeof(uint2);
    size_t need = (size_t)(q - (char*)d_ws);
    if (ws_size >= need && NB <= NBMAX) {
      u32* xw = (u32*)bufP;
      (void)hipMemsetAsync(ghX, 0, 2 * NBMAX * sizeof(int), stream);
      hist_conv<<<HISTB + CONVB, 256, 0, stream>>>(
          x_rows, nnz_x, adj_rows, nnz_adj, ghX, ghA,
          (const float2*)W, Wbf, wwords);
      scan_buckets<<<2, NBMAX, 0, stream>>>(ghX, baseX, curX, ghA, baseA, curA, NB);
      partition_both<<<ntX, 256, 0, stream>>>(
          x_rows, x_cols, x_vals, nnz_x, ntX, curX, bufP,
          adj_rows, adj_cols, adj_vals, nnz_adj, curA, bufP);
      bucket_sort_both<<<NB, 256, 0, stream>>>(
          NB, baseX, bufP, bufSX, rpX, baseA, bufP, bufSA, rpA, N);
      partition_both<<<ntA, 256, 0, stream>>>(
          x_rows, x_cols, x_vals, nnz_x, 0, curX, bufP,
          adj_rows, adj_cols, adj_vals, nnz_adj, curA, bufP);
      bucket_sort_both<<<NB, 256, 0, stream>>>(
          0, baseX, bufP, bufSX, rpX, baseA, bufP, bufSA, rpA, N);
      pull_x<<<(N + 3) / 4, 256, 0, stream>>>(rpX, bufSX, Wbf, xw, N);
      pull_a<<<(N + 3) / 4, 256, 0, stream>>>(rpA, bufSA, xw, (float2*)out, N);
      return;
    }
  }

  // --- Last resort: atomic push (needs only N*ODIM floats).
  {
    float* xwf = (float*)d_ws;
    const size_t out_bytes = (size_t)out_size * sizeof(float);
    (void)hipMemsetAsync(xwf, 0, out_bytes, stream);
    (void)hipMemsetAsync(out, 0, out_bytes, stream);
    spmm_scatter<<<(nnz_x + 1) / 2, 256, 0, stream>>>(x_rows, x_cols, x_vals, W, xwf, nnz_x);
    spmm_scatter<<<(nnz_adj + 1) / 2, 256, 0, stream>>>(adj_rows, adj_cols, adj_vals, xwf, out, nnz_adj);
    relu_inplace<<<2048, 256, 0, stream>>>(out, (long)out_size / 4);
  }
}

// Round 15
// 172.687 us; speedup vs baseline: 1.8589x; 1.0503x over previous
//
#include <hip/hip_runtime.h>

#define ODIM 128          // OUT_DIM
#define BROWS 128         // rows per bucket
#define NBMAX 512         // max buckets (N/128 = 391 for N=50000)
#define TILE 4096         // edges per partition tile (57KB LDS, 2 blocks/CU, 84B runs)
#define CMASK 0x1FFFFu    // low 17 bits of meta = col
#define HISTB 1024        // hist blocks in fused hist+conv kernel
#define CONVB 512         // conv blocks in fused hist+conv kernel

typedef unsigned u32;

__device__ inline unsigned f2bf(float x) {  // fp32 -> bf16 bits, RNE
  unsigned u = __float_as_uint(x);
  return (u + 0x7fffu + ((u >> 16) & 1u)) >> 16;
}

// ---- fused: bucket histogram (blocks < HISTB) + W->bf16 convert (rest) ----

__global__ __launch_bounds__(256) void hist_conv(
    const int* __restrict__ xr, int nx, const int* __restrict__ ar, int na,
    int* __restrict__ ghX, int* __restrict__ ghA,
    const float2* __restrict__ W2, u32* __restrict__ Wbf, int wwords) {
  __shared__ int lh[2 * NBMAX];
  if ((int)blockIdx.x >= HISTB) {
    int i = (blockIdx.x - HISTB) * 256 + threadIdx.x;
    int stride = CONVB * 256;
    for (; i < wwords; i += stride) {
      float2 w = W2[i];
      Wbf[i] = f2bf(w.x) | (f2bf(w.y) << 16);
    }
    return;
  }
  for (int i = threadIdx.x; i < 2 * NBMAX; i += 256) lh[i] = 0;
  __syncthreads();
  int total = nx + na;
  for (int i = blockIdx.x * 256 + threadIdx.x; i < total; i += HISTB * 256) {
    if (i < nx) atomicAdd(&lh[xr[i] >> 7], 1);
    else        atomicAdd(&lh[NBMAX + (ar[i - nx] >> 7)], 1);
  }
  __syncthreads();
  for (int b = threadIdx.x; b < NBMAX; b += 256) {
    if (lh[b])         atomicAdd(&ghX[b], lh[b]);
    if (lh[NBMAX + b]) atomicAdd(&ghA[b], lh[NBMAX + b]);
  }
}

// ---------------- bucket scan (block 0: X, block 1: A) ----------------

__global__ __launch_bounds__(NBMAX) void scan_buckets(
    int* __restrict__ ghX, int* __restrict__ baseX, int* __restrict__ curX,
    int* __restrict__ ghA, int* __restrict__ baseA, int* __restrict__ curA,
    int nb) {
  int* gh   = blockIdx.x ? ghA   : ghX;
  int* base = blockIdx.x ? baseA : baseX;
  int* cur  = blockIdx.x ? curA  : curX;
  __shared__ int s[NBMAX];
  int tid = threadIdx.x;
  int v = (tid < nb) ? gh[tid] : 0;
  s[tid] = v;
  __syncthreads();
  for (int off = 1; off < NBMAX; off <<= 1) {
    int t = (tid >= off) ? s[tid - off] : 0;
    __syncthreads();
    s[tid] += t;
    __syncthreads();
  }
  int excl = s[tid] - v;
  if (tid < nb) { base[tid] = excl; cur[tid] = excl; }
  if (tid == NBMAX - 1) base[nb] = s[tid];
}

// ---- pass 1: tile counting-sort into buckets (X and A fused in one grid) ----

__global__ __launch_bounds__(256) void partition_both(
    const int* __restrict__ xr, const int* __restrict__ xc,
    const float* __restrict__ xv, int nx, int ntX,
    int* __restrict__ curX, uint2* __restrict__ outX,
    const int* __restrict__ ar, const int* __restrict__ ac,
    const float* __restrict__ av, int na,
    int* __restrict__ curA, uint2* __restrict__ outA) {
  __shared__ uint2 pay[TILE];            // 32KB packed (meta, val)
  __shared__ unsigned short bkt[TILE];   // 8KB
  __shared__ unsigned short perm[TILE];  // 8KB
  __shared__ int hist[NBMAX];
  __shared__ int scn[NBMAX];
  __shared__ int cur[NBMAX];
  __shared__ int gbase[NBMAX];
  __shared__ int part[256];

  const int* rows; const int* cols; const float* vals;
  int nnz; int* gcur; uint2* outbuf; int tile;
  if ((int)blockIdx.x < ntX) {
    rows = xr; cols = xc; vals = xv; nnz = nx; gcur = curX; outbuf = outX;
    tile = blockIdx.x;
  } else {
    rows = ar; cols = ac; vals = av; nnz = na; gcur = curA; outbuf = outA;
    tile = blockIdx.x - ntX;
  }

  int tid = threadIdx.x;
  int tbase = tile * TILE;
  int cnt = nnz - tbase; if (cnt > TILE) cnt = TILE;

  for (int b = tid; b < NBMAX; b += 256) hist[b] = 0;
  __syncthreads();

  for (int j = tid; j < cnt; j += 256) {
    int r = rows[tbase + j];
    int c = cols[tbase + j];
    float v = vals[tbase + j];
    unsigned b = (unsigned)r >> 7;
    bkt[j] = (unsigned short)b;
    pay[j] = make_uint2(((unsigned)(r & 127) << 17) | (unsigned)c, __float_as_uint(v));
    atomicAdd(&hist[b], 1);
  }
  __syncthreads();

  int h0 = hist[2 * tid], h1 = hist[2 * tid + 1];
  int psum = h0 + h1;
  part[tid] = psum;
  __syncthreads();
  for (int off = 1; off < 256; off <<= 1) {
    int t = (tid >= off) ? part[tid - off] : 0;
    __syncthreads();
    part[tid] += t;
    __syncthreads();
  }
  int excl = part[tid] - psum;
  scn[2 * tid] = excl;     scn[2 * tid + 1] = excl + h0;
  cur[2 * tid] = excl;     cur[2 * tid + 1] = excl + h0;
  __syncthreads();

  for (int j = tid; j < cnt; j += 256) {
    int pos = atomicAdd(&cur[bkt[j]], 1);
    perm[pos] = (unsigned short)j;
  }
  for (int b = tid; b < NBMAX; b += 256) {
    int c = hist[b];
    if (c) gbase[b] = atomicAdd(&gcur[b], c);
  }
  __syncthreads();

  for (int p = tid; p < cnt; p += 256) {
    int j = perm[p];
    int b = bkt[j];
    outbuf[gbase[b] + (p - scn[b])] = pay[j];
  }
}

// ---- pass 2: per-bucket exact row sort + rowptr (X and A fused) ----

__global__ __launch_bounds__(256) void bucket_sort_both(
    int nbX,
    const int* __restrict__ baseX, const uint2* __restrict__ binX,
    uint2* __restrict__ boutX, int* __restrict__ rpX,
    const int* __restrict__ baseA, const uint2* __restrict__ binA,
    uint2* __restrict__ boutA, int* __restrict__ rpA, int N) {
  __shared__ int hist[BROWS], scn[BROWS], cur[BROWS];
  const int* base; const uint2* bufin; uint2* bufout; int* rowptr; int b;
  if ((int)blockIdx.x < nbX) {
    base = baseX; bufin = binX; bufout = boutX; rowptr = rpX; b = blockIdx.x;
  } else {
    base = baseA; bufin = binA; bufout = boutA; rowptr = rpA; b = blockIdx.x - nbX;
  }
  int tid = threadIdx.x;
  int e0 = base[b], ecnt = base[b + 1] - e0;

  if (tid < BROWS) hist[tid] = 0;
  __syncthreads();
  for (int j = tid; j < ecnt; j += 256)
    atomicAdd(&hist[bufin[e0 + j].x >> 17], 1);
  __syncthreads();

  int v = (tid < BROWS) ? hist[tid] : 0;
  if (tid < BROWS) scn[tid] = v;
  __syncthreads();
  for (int off = 1; off < BROWS; off <<= 1) {
    int t = (tid < BROWS && tid >= off) ? scn[tid - off] : 0;
    __syncthreads();
    if (tid < BROWS) scn[tid] += t;
    __syncthreads();
  }
  if (tid < BROWS) {
    int excl = scn[tid] - v;
    cur[tid] = excl;
    int node = b * BROWS + tid;
    if (node <= N) rowptr[node] = e0 + excl;
  }
  __syncthreads();

  for (int j = tid; j < ecnt; j += 256) {
    uint2 e = bufin[e0 + j];
    int pos = atomicAdd(&cur[e.x >> 17], 1);
    bufout[e0 + pos] = e;
  }
}

// ---------------- pulls (wave per row, register accumulate, 8-deep) ---------
// Table word l of a row = bf16(dim 2l) | bf16(dim 2l+1)<<16.

__global__ __launch_bounds__(256) void pull_x(
    const int* __restrict__ rowptr, const uint2* __restrict__ cv,
    const u32* __restrict__ Wbf, unsigned* __restrict__ xw, int nrows) {
  int lane = threadIdx.x & 63;
  int r = blockIdx.x * 4 + (threadIdx.x >> 6);
  if (r >= nrows) return;
  int e = rowptr[r], end = rowptr[r + 1];
  float acc0[8], acc1[8];
#pragma unroll
  for (int u = 0; u < 8; ++u) { acc0[u] = 0.f; acc1[u] = 0.f; }
  for (; e + 7 < end; e += 8) {
    uint2 ed[8]; unsigned xg[8];
#pragma unroll
    for (int u = 0; u < 8; ++u) ed[u] = cv[e + u];
#pragma unroll
    for (int u = 0; u < 8; ++u)
      xg[u] = Wbf[(size_t)(ed[u].x & CMASK) * 64 + lane];
#pragma unroll
    for (int u = 0; u < 8; ++u) {
      float v = __uint_as_float(ed[u].y);
      acc0[u] += v * __uint_as_float(xg[u] << 16);
      acc1[u] += v * __uint_as_float(xg[u] & 0xffff0000u);
    }
  }
  for (; e + 1 < end; e += 2) {
    uint2 ea = cv[e], eb = cv[e + 1];
    unsigned ua = Wbf[(size_t)(ea.x & CMASK) * 64 + lane];
    unsigned ub = Wbf[(size_t)(eb.x & CMASK) * 64 + lane];
    float va = __uint_as_float(ea.y), vb = __uint_as_float(eb.y);
    acc0[0] += va * __uint_as_float(ua << 16);
    acc1[0] += va * __uint_as_float(ua & 0xffff0000u);
    acc0[1] += vb * __uint_as_float(ub << 16);
    acc1[1] += vb * __uint_as_float(ub & 0xffff0000u);
  }
  if (e < end) {
    uint2 ea = cv[e];
    unsigned ua = Wbf[(size_t)(ea.x & CMASK) * 64 + lane];
    float va = __uint_as_float(ea.y);
    acc0[2] += va * __uint_as_float(ua << 16);
    acc1[2] += va * __uint_as_float(ua & 0xffff0000u);
  }
  float o0 = ((acc0[0] + acc0[1]) + (acc0[2] + acc0[3])) +
             ((acc0[4] + acc0[5]) + (acc0[6] + acc0[7]));
  float o1 = ((acc1[0] + acc1[1]) + (acc1[2] + acc1[3])) +
             ((acc1[4] + acc1[5]) + (acc1[6] + acc1[7]));
  xw[(size_t)r * 64 + lane] = f2bf(o0) | (f2bf(o1) << 16);
}

__global__ __launch_bounds__(256) void pull_a(
    const int* __restrict__ rowptr, const uint2* __restrict__ cv,
    const unsigned* __restrict__ xw, float2* __restrict__ out, int nrows) {
  int lane = threadIdx.x & 63;
  int r = blockIdx.x * 4 + (threadIdx.x >> 6);
  if (r >= nrows) return;
  int e = rowptr[r], end = rowptr[r + 1];
  float acc0[8], acc1[8];
#pragma unroll
  for (int u = 0; u < 8; ++u) { acc0[u] = 0.f; acc1[u] = 0.f; }
  for (; e + 7 < end; e += 8) {
    uint2 ed[8]; unsigned xg[8];
#pragma unroll
    for (int u = 0; u < 8; ++u) ed[u] = cv[e + u];
#pragma unroll
    for (int u = 0; u < 8; ++u)
      xg[u] = xw[(size_t)(ed[u].x & CMASK) * 64 + lane];
#pragma unroll
    for (int u = 0; u < 8; ++u) {
      float v = __uint_as_float(ed[u].y);
      acc0[u] += v * __uint_as_float(xg[u] << 16);
      acc1[u] += v * __uint_as_float(xg[u] & 0xffff0000u);
    }
  }
  for (; e + 1 < end; e += 2) {
    uint2 ea = cv[e], eb = cv[e + 1];
    unsigned ua = xw[(size_t)(ea.x & CMASK) * 64 + lane];
    unsigned ub = xw[(size_t)(eb.x & CMASK) * 64 + lane];
    float va = __uint_as_float(ea.y), vb = __uint_as_float(eb.y);
    acc0[0] += va * __uint_as_float(ua << 16);
    acc1[0] += va * __uint_as_float(ua & 0xffff0000u);
    acc0[1] += vb * __uint_as_float(ub << 16);
    acc1[1] += vb * __uint_as_float(ub & 0xffff0000u);
  }
  if (e < end) {
    uint2 ea = cv[e];
    unsigned ua = xw[(size_t)(ea.x & CMASK) * 64 + lane];
    float va = __uint_as_float(ea.y);
    acc0[2] += va * __uint_as_float(ua << 16);
    acc1[2] += va * __uint_as_float(ua & 0xffff0000u);
  }
  float o0 = ((acc0[0] + acc0[1]) + (acc0[2] + acc0[3])) +
             ((acc0[4] + acc0[5]) + (acc0[6] + acc0[7]));
  float o1 = ((acc1[0] + acc1[1]) + (acc1[2] + acc1[3])) +
             ((acc1[4] + acc1[5]) + (acc1[6] + acc1[7]));
  out[(size_t)r * 64 + lane] = make_float2(fmaxf(o0, 0.f), fmaxf(o1, 0.f));
}

// ---------------- fallback (atomic push) ----------------

__global__ __launch_bounds__(256) void spmm_scatter(
    const int* __restrict__ rows, const int* __restrict__ cols,
    const float* __restrict__ vals, const float* __restrict__ B,
    float* __restrict__ out, int nnz) {
  int e = blockIdx.x * 2 + (threadIdx.x >> 7);
  int d = threadIdx.x & (ODIM - 1);
  if (e >= nnz) return;
  atomicAdd(&out[(size_t)rows[e] * ODIM + d],
            vals[e] * B[(size_t)cols[e] * ODIM + d]);
}

__global__ __launch_bounds__(256) void relu_inplace(float* __restrict__ p, long n4) {
  long i = (long)blockIdx.x * blockDim.x + threadIdx.x;
  long stride = (long)gridDim.x * blockDim.x;
  float4* p4 = (float4*)p;
  for (long j = i; j < n4; j += stride) {
    float4 v = p4[j];
    v.x = fmaxf(v.x, 0.f); v.y = fmaxf(v.y, 0.f);
    v.z = fmaxf(v.z, 0.f); v.w = fmaxf(v.w, 0.f);
    p4[j] = v;
  }
}

extern "C" void kernel_launch(void* const* d_in, const int* in_sizes, int n_in,
                              void* d_out, int out_size, void* d_ws, size_t ws_size,
                              hipStream_t stream) {
  const int*   x_rows   = (const int*)d_in[0];
  const int*   x_cols   = (const int*)d_in[1];
  const float* x_vals   = (const float*)d_in[2];
  const int*   adj_rows = (const int*)d_in[3];
  const int*   adj_cols = (const int*)d_in[4];
  const float* adj_vals = (const float*)d_in[5];
  const float* W        = (const float*)d_in[6];

  const int nnz_x   = in_sizes[0];
  const int nnz_adj = in_sizes[3];
  const int wlen    = in_sizes[6];              // IN_DIM * ODIM
  const int N       = out_size / ODIM;          // 50000
  const int NB      = (N + BROWS - 1) / BROWS;  // 391
  const int ntX     = (nnz_x + TILE - 1) / TILE;
  const int ntA     = (nnz_adj + TILE - 1) / TILE;
  const int wwords  = wlen / 2;                 // packed bf16 words

  float* out = (float*)d_out;

  // Common control block
  char* p = (char*)d_ws;
  int* ghX   = (int*)p;  p += NBMAX * sizeof(int);
  int* ghA   = (int*)p;  p += NBMAX * sizeof(int);        // adjacent: one memset
  int* baseX = (int*)p;  p += (NBMAX + 1) * sizeof(int);
  int* baseA = (int*)p;  p += (NBMAX + 1) * sizeof(int);
  int* curX  = (int*)p;  p += NBMAX * sizeof(int);
  int* curA  = (int*)p;  p += NBMAX * sizeof(int);
  int* rpX   = (int*)p;  p += (size_t)(N + 1) * sizeof(int);
  int* rpA   = (int*)p;  p += (size_t)(N + 1) * sizeof(int);
  p = (char*)(((uintptr_t)p + 255) & ~(uintptr_t)255);
  u32* Wbf   = (u32*)p;  p += (size_t)wwords * sizeof(u32);
  p = (char*)(((uintptr_t)p + 255) & ~(uintptr_t)255);
  char* bufs = p;

  const size_t xw_bytes = (size_t)N * 64 * sizeof(u32);

  // --- Fused layout: separate ping buffers for X and A (one partition launch).
  // xw aliases bufPX..bufPA (dead after bucket_sort_both).
  {
    char* q = bufs;
    uint2* bufPX = (uint2*)q; q += (size_t)nnz_x * sizeof(uint2);
    uint2* bufPA = (uint2*)q; q += (size_t)nnz_adj * sizeof(uint2);
    uint2* bufSX = (uint2*)q; q += (size_t)nnz_x * sizeof(uint2);
    uint2* bufSA = (uint2*)q; q += (size_t)nnz_adj * sizeof(uint2);
    size_t need = (size_t)(q - (char*)d_ws);
    bool xw_fits = xw_bytes <= ((size_t)nnz_x + nnz_adj) * sizeof(uint2);
    if (ws_size >= need && NB <= NBMAX && xw_fits) {
      u32* xw = (u32*)bufPX;
      (void)hipMemsetAsync(ghX, 0, 2 * NBMAX * sizeof(int), stream);
      hist_conv<<<HISTB + CONVB, 256, 0, stream>>>(
          x_rows, nnz_x, adj_rows, nnz_adj, ghX, ghA,
          (const float2*)W, Wbf, wwords);
      scan_buckets<<<2, NBMAX, 0, stream>>>(ghX, baseX, curX, ghA, baseA, curA, NB);
      partition_both<<<ntX + ntA, 256, 0, stream>>>(
          x_rows, x_cols, x_vals, nnz_x, ntX, curX, bufPX,
          adj_rows, adj_cols, adj_vals, nnz_adj, curA, bufPA);
      bucket_sort_both<<<2 * NB, 256, 0, stream>>>(
          NB, baseX, bufPX, bufSX, rpX, baseA, bufPA, bufSA, rpA, N);
      pull_x<<<(N + 3) / 4, 256, 0, stream>>>(rpX, bufSX, Wbf, xw, N);
      pull_a<<<(N + 3) / 4, 256, 0, stream>>>(rpA, bufSA, xw, (float2*)out, N);
      return;
    }
  }

  // --- Sequential layout (shared ping buffer) if ws smaller.
  {
    size_t bufP_elems = (size_t)(nnz_x > nnz_adj ? nnz_x : nnz_adj);
    if (bufP_elems * sizeof(uint2) < xw_bytes)
      bufP_elems = (xw_bytes + sizeof(uint2) - 1) / sizeof(uint2);
    char* q = bufs;
    uint2* bufP  = (uint2*)q; q += bufP_elems * sizeof(uint2);
    uint2* bufSX = (uint2*)q; q += (size_t)nnz_x * sizeof(uint2);
    uint2* bufSA = (uint2*)q; q += (size_t)nnz_adj * sizeof(uint2);
    size_t need = (size_t)(q - (char*)d_ws);
    if (ws_size >= need && NB <= NBMAX) {
      u32* xw = (u32*)bufP;
      (void)hipMemsetAsync(ghX, 0, 2 * NBMAX * sizeof(int), stream);
      hist_conv<<<HISTB + CONVB, 256, 0, stream>>>(
          x_rows, nnz_x, adj_rows, nnz_adj, ghX, ghA,
          (const float2*)W, Wbf, wwords);
      scan_buckets<<<2, NBMAX, 0, stream>>>(ghX, baseX, curX, ghA, baseA, curA, NB);
      partition_both<<<ntX, 256, 0, stream>>>(
          x_rows, x_cols, x_vals, nnz_x, ntX, curX, bufP,
          adj_rows, adj_cols, adj_vals, nnz_adj, curA, bufP);
      bucket_sort_both<<<NB, 256, 0, stream>>>(
          NB, baseX, bufP, bufSX, rpX, baseA, bufP, bufSA, rpA, N);
      partition_both<<<ntA, 256, 0, stream>>>(
          x_rows, x_cols, x_vals, nnz_x, 0, curX, bufP,
          adj_rows, adj_cols, adj_vals, nnz_adj, curA, bufP);
      bucket_sort_both<<<NB, 256, 0, stream>>>(
          0, baseX, bufP, bufSX, rpX, baseA, bufP, bufSA, rpA, N);
      pull_x<<<(N + 3) / 4, 256, 0, stream>>>(rpX, bufSX, Wbf, xw, N);
      pull_a<<<(N + 3) / 4, 256, 0, stream>>>(rpA, bufSA, xw, (float2*)out, N);
      return;
    }
  }

  // --- Last resort: atomic push (needs only N*ODIM floats).
  {
    float* xwf = (float*)d_ws;
    const size_t out_bytes = (size_t)out_size * sizeof(float);
    (void)hipMemsetAsync(xwf, 0, out_bytes, stream);
    (void)hipMemsetAsync(out, 0, out_bytes, stream);
    spmm_scatter<<<(nnz_x + 1) / 2, 256, 0, stream>>>(x_rows, x_cols, x_vals, W, xwf, nnz_x);
    spmm_scatter<<<(nnz_adj + 1) / 2, 256, 0, stream>>>(adj_rows, adj_cols, adj_vals, xwf, out, nnz_adj);
    relu_inplace<<<2048, 256, 0, stream>>>(out, (long)out_size / 4);
  }
}